// Round 1
// baseline (5761.732 us; speedup 1.0000x reference)
//
#include <hip/hip_runtime.h>
#include <hip/hip_bf16.h>
#include <math.h>

#define DD   512
#define HN   8
#define DHD  64
#define LL   6
#define DFF_ 2048
#define VV   256
#define KB_  5
#define PP   2048
#define EPS_ 1e-5f
#define TAU_ 0.1f

// ---------------- helpers ----------------
__device__ __forceinline__ float wave_sum(float v) {
#pragma unroll
  for (int m = 32; m >= 1; m >>= 1) v += __shfl_xor(v, m, 64);
  return v;
}

// ---------------- embedding: x = mean_k emb[patch[k]], tok = emb[patch[K-1]] ----------------
__global__ __launch_bounds__(256) void embed_mean_kernel(const int* __restrict__ bytes,
                                                         const float* __restrict__ emb,
                                                         float* __restrict__ x,
                                                         float* __restrict__ tok) {
  const int p = blockIdx.x;
  const int d = threadIdx.x * 2;
  float a0 = 0.f, a1 = 0.f;
  int last = 0;
#pragma unroll
  for (int k = 0; k < KB_; ++k) {
    const int idx = bytes[p * KB_ + k];
    last = idx;
    const float* e = emb + (size_t)idx * DD + d;
    a0 += e[0]; a1 += e[1];
  }
  x[(size_t)p * DD + d]     = a0 * 0.2f;
  x[(size_t)p * DD + d + 1] = a1 * 0.2f;
  const float* e = emb + (size_t)last * DD + d;
  tok[(size_t)p * DD + d]     = e[0];
  tok[(size_t)p * DD + d + 1] = e[1];
}

// ---------------- generic GEMM: C[M x N] = A[M x Kd] @ W[N x Kd]^T + bias ----------------
template <int RELU>
__global__ __launch_bounds__(256) void gemm_bias_kernel(
    const float* __restrict__ A, int lda,
    const float* __restrict__ W, int ldw,
    const float* __restrict__ bias,
    float* __restrict__ C, int ldc,
    int M, int Nn, int Kd) {
  __shared__ float As[32][68];
  __shared__ float Bs[32][68];
  const int bm = blockIdx.y * 64;
  const int bn = blockIdx.x * 64;
  const int tid = threadIdx.x;
  const int tx = tid & 15;
  const int ty = tid >> 4;
  const int lr = tid >> 3;         // 0..31
  const int lc = (tid & 7) * 4;    // 0..28

  float acc[4][4];
#pragma unroll
  for (int i = 0; i < 4; ++i)
#pragma unroll
    for (int j = 0; j < 4; ++j) acc[i][j] = 0.f;

  for (int k0 = 0; k0 < Kd; k0 += 32) {
    __syncthreads();
    const float4 a0 = *(const float4*)&A[(size_t)(bm + lr) * lda + k0 + lc];
    const float4 a1 = *(const float4*)&A[(size_t)(bm + lr + 32) * lda + k0 + lc];
    const float4 w0 = *(const float4*)&W[(size_t)(bn + lr) * ldw + k0 + lc];
    const float4 w1 = *(const float4*)&W[(size_t)(bn + lr + 32) * ldw + k0 + lc];
    As[lc + 0][lr] = a0.x; As[lc + 1][lr] = a0.y; As[lc + 2][lr] = a0.z; As[lc + 3][lr] = a0.w;
    As[lc + 0][lr + 32] = a1.x; As[lc + 1][lr + 32] = a1.y; As[lc + 2][lr + 32] = a1.z; As[lc + 3][lr + 32] = a1.w;
    Bs[lc + 0][lr] = w0.x; Bs[lc + 1][lr] = w0.y; Bs[lc + 2][lr] = w0.z; Bs[lc + 3][lr] = w0.w;
    Bs[lc + 0][lr + 32] = w1.x; Bs[lc + 1][lr + 32] = w1.y; Bs[lc + 2][lr + 32] = w1.z; Bs[lc + 3][lr + 32] = w1.w;
    __syncthreads();
#pragma unroll
    for (int kk = 0; kk < 32; ++kk) {
      const float4 a4 = *(const float4*)&As[kk][ty * 4];
      const float4 b4 = *(const float4*)&Bs[kk][tx * 4];
      const float av[4] = {a4.x, a4.y, a4.z, a4.w};
      const float bv[4] = {b4.x, b4.y, b4.z, b4.w};
#pragma unroll
      for (int i = 0; i < 4; ++i)
#pragma unroll
        for (int j = 0; j < 4; ++j) acc[i][j] = fmaf(av[i], bv[j], acc[i][j]);
    }
  }

  const float4 bv4 = *(const float4*)&bias[bn + tx * 4];
  const float bb[4] = {bv4.x, bv4.y, bv4.z, bv4.w};
#pragma unroll
  for (int i = 0; i < 4; ++i) {
    float4 c;
    c.x = acc[i][0] + bb[0];
    c.y = acc[i][1] + bb[1];
    c.z = acc[i][2] + bb[2];
    c.w = acc[i][3] + bb[3];
    if (RELU) {
      c.x = fmaxf(c.x, 0.f); c.y = fmaxf(c.y, 0.f);
      c.z = fmaxf(c.z, 0.f); c.w = fmaxf(c.w, 0.f);
    }
    *(float4*)&C[(size_t)(bm + ty * 4 + i) * ldc + bn + tx * 4] = c;
  }
}

// ---------------- flash attention (fp32, online softmax) ----------------
// qkv: P x 3D, q at col h*64, k at D + h*64, v at 2D + h*64. out: P x D.
__global__ __launch_bounds__(256) void flash_attn_kernel(const float* __restrict__ qkv,
                                                         float* __restrict__ out) {
  const int h = blockIdx.y;
  const int q0 = blockIdx.x * 32;
  const int tid = threadIdx.x;
  const int lane = tid & 63;
  const int rl = tid >> 3;   // 0..31: local q row
  const int cg = lane & 7;   // 0..7: column group

  __shared__ float Qs[32][68];
  __shared__ float Ks[64][68];
  __shared__ float Vs[64][68];
  __shared__ float Ps[32][65];

  {
    const int r = tid >> 3, c0 = (tid & 7) * 8;
    const float* src = qkv + (size_t)(q0 + r) * (3 * DD) + h * DHD + c0;
    *(float4*)&Qs[r][c0]     = *(const float4*)src;
    *(float4*)&Qs[r][c0 + 4] = *(const float4*)(src + 4);
  }

  float m = -INFINITY, lsum = 0.f;
  float o[8];
#pragma unroll
  for (int j = 0; j < 8; ++j) o[j] = 0.f;

  for (int k0 = 0; k0 < PP; k0 += 64) {
    __syncthreads();
    {
      const int r = tid >> 2, c0 = (tid & 3) * 16;
      const float* ksrc = qkv + (size_t)(k0 + r) * (3 * DD) + DD + h * DHD + c0;
      const float* vsrc = ksrc + DD;
#pragma unroll
      for (int j = 0; j < 16; j += 4) {
        *(float4*)&Ks[r][c0 + j] = *(const float4*)(ksrc + j);
        *(float4*)&Vs[r][c0 + j] = *(const float4*)(vsrc + j);
      }
    }
    __syncthreads();

    float s[8];
#pragma unroll
    for (int j = 0; j < 8; ++j) s[j] = 0.f;
#pragma unroll
    for (int kk = 0; kk < DHD; kk += 4) {
      const float4 q4 = *(const float4*)&Qs[rl][kk];
#pragma unroll
      for (int j = 0; j < 8; ++j) {
        const float4 k4 = *(const float4*)&Ks[cg + 8 * j][kk];
        s[j] = fmaf(q4.x, k4.x, fmaf(q4.y, k4.y, fmaf(q4.z, k4.z, fmaf(q4.w, k4.w, s[j]))));
      }
    }
#pragma unroll
    for (int j = 0; j < 8; ++j) s[j] *= 0.125f;  // 1/sqrt(64)

    float mx = s[0];
#pragma unroll
    for (int j = 1; j < 8; ++j) mx = fmaxf(mx, s[j]);
#pragma unroll
    for (int t = 1; t < 8; t <<= 1) mx = fmaxf(mx, __shfl_xor(mx, t, 64));
    const float mnew = fmaxf(m, mx);
    const float corr = expf(m - mnew);
    float psum = 0.f;
#pragma unroll
    for (int j = 0; j < 8; ++j) { s[j] = expf(s[j] - mnew); psum += s[j]; }
#pragma unroll
    for (int t = 1; t < 8; t <<= 1) psum += __shfl_xor(psum, t, 64);
    lsum = lsum * corr + psum;
    m = mnew;
#pragma unroll
    for (int j = 0; j < 8; ++j) o[j] *= corr;
#pragma unroll
    for (int j = 0; j < 8; ++j) Ps[rl][cg + 8 * j] = s[j];
    __syncthreads();
#pragma unroll
    for (int c = 0; c < 64; ++c) {
      const float pv = Ps[rl][c];
      const float4 v0 = *(const float4*)&Vs[c][cg * 8];
      const float4 v1 = *(const float4*)&Vs[c][cg * 8 + 4];
      o[0] = fmaf(pv, v0.x, o[0]); o[1] = fmaf(pv, v0.y, o[1]);
      o[2] = fmaf(pv, v0.z, o[2]); o[3] = fmaf(pv, v0.w, o[3]);
      o[4] = fmaf(pv, v1.x, o[4]); o[5] = fmaf(pv, v1.y, o[5]);
      o[6] = fmaf(pv, v1.z, o[6]); o[7] = fmaf(pv, v1.w, o[7]);
    }
  }

  const float inv = 1.f / lsum;
  float* dst = out + (size_t)(q0 + rl) * DD + h * DHD + cg * 8;
  float4 r0, r1;
  r0.x = o[0] * inv; r0.y = o[1] * inv; r0.z = o[2] * inv; r0.w = o[3] * inv;
  r1.x = o[4] * inv; r1.y = o[5] * inv; r1.z = o[6] * inv; r1.w = o[7] * inv;
  *(float4*)dst = r0;
  *(float4*)(dst + 4) = r1;
}

// ---------------- LN(x + res) * w + b, one wave per row ----------------
__global__ __launch_bounds__(256) void ln_residual_kernel(const float* __restrict__ xin,
                                                          const float* __restrict__ res,
                                                          const float* __restrict__ w,
                                                          const float* __restrict__ b,
                                                          float* __restrict__ out) {
  const int row = blockIdx.x * 4 + (threadIdx.x >> 6);
  const int lane = threadIdx.x & 63;
  const float* xr = xin + (size_t)row * DD + lane * 8;
  const float* rr = res + (size_t)row * DD + lane * 8;
  float v[8];
  {
    const float4 a0 = *(const float4*)xr;
    const float4 a1 = *(const float4*)(xr + 4);
    const float4 r0 = *(const float4*)rr;
    const float4 r1 = *(const float4*)(rr + 4);
    v[0] = a0.x + r0.x; v[1] = a0.y + r0.y; v[2] = a0.z + r0.z; v[3] = a0.w + r0.w;
    v[4] = a1.x + r1.x; v[5] = a1.y + r1.y; v[6] = a1.z + r1.z; v[7] = a1.w + r1.w;
  }
  float sum = 0.f;
#pragma unroll
  for (int j = 0; j < 8; ++j) sum += v[j];
  sum = wave_sum(sum);
  const float mean = sum * (1.f / DD);
  float sq = 0.f;
#pragma unroll
  for (int j = 0; j < 8; ++j) { const float d = v[j] - mean; sq += d * d; }
  sq = wave_sum(sq);
  const float rstd = rsqrtf(sq * (1.f / DD) + EPS_);
  const float* wp = w + lane * 8;
  const float* bp = b + lane * 8;
  float* op = out + (size_t)row * DD + lane * 8;
  float4 o0, o1;
  o0.x = (v[0] - mean) * rstd * wp[0] + bp[0];
  o0.y = (v[1] - mean) * rstd * wp[1] + bp[1];
  o0.z = (v[2] - mean) * rstd * wp[2] + bp[2];
  o0.w = (v[3] - mean) * rstd * wp[3] + bp[3];
  o1.x = (v[4] - mean) * rstd * wp[4] + bp[4];
  o1.y = (v[5] - mean) * rstd * wp[5] + bp[5];
  o1.z = (v[6] - mean) * rstd * wp[6] + bp[6];
  o1.w = (v[7] - mean) * rstd * wp[7] + bp[7];
  *(float4*)op = o0;
  *(float4*)(op + 4) = o1;
}

// ---------------- gate + mix: x = (||enc|| > TAU) ? a*enc + (1-a)*tok : tok ----------------
__global__ __launch_bounds__(256) void gate_mix_kernel(const float* __restrict__ enc,
                                                       const float* __restrict__ tok,
                                                       const float* __restrict__ alpha_p,
                                                       float* __restrict__ x) {
  const int row = blockIdx.x * 4 + (threadIdx.x >> 6);
  const int lane = threadIdx.x & 63;
  const float* er = enc + (size_t)row * DD + lane * 8;
  const float* tr = tok + (size_t)row * DD + lane * 8;
  float e[8], t[8];
  {
    const float4 a0 = *(const float4*)er;
    const float4 a1 = *(const float4*)(er + 4);
    const float4 b0 = *(const float4*)tr;
    const float4 b1 = *(const float4*)(tr + 4);
    e[0] = a0.x; e[1] = a0.y; e[2] = a0.z; e[3] = a0.w;
    e[4] = a1.x; e[5] = a1.y; e[6] = a1.z; e[7] = a1.w;
    t[0] = b0.x; t[1] = b0.y; t[2] = b0.z; t[3] = b0.w;
    t[4] = b1.x; t[5] = b1.y; t[6] = b1.z; t[7] = b1.w;
  }
  float sq = 0.f;
#pragma unroll
  for (int j = 0; j < 8; ++j) sq += e[j] * e[j];
  sq = wave_sum(sq);
  const bool gate = sq > TAU_ * TAU_;
  const float a = *alpha_p;
  float* op = x + (size_t)row * DD + lane * 8;
  float4 o0, o1;
  if (gate) {
    o0.x = a * e[0] + (1.f - a) * t[0]; o0.y = a * e[1] + (1.f - a) * t[1];
    o0.z = a * e[2] + (1.f - a) * t[2]; o0.w = a * e[3] + (1.f - a) * t[3];
    o1.x = a * e[4] + (1.f - a) * t[4]; o1.y = a * e[5] + (1.f - a) * t[5];
    o1.z = a * e[6] + (1.f - a) * t[6]; o1.w = a * e[7] + (1.f - a) * t[7];
  } else {
    o0.x = t[0]; o0.y = t[1]; o0.z = t[2]; o0.w = t[3];
    o1.x = t[4]; o1.y = t[5]; o1.z = t[6]; o1.w = t[7];
  }
  *(float4*)op = o0;
  *(float4*)(op + 4) = o1;
}

// ---------------- copy (float4) ----------------
__global__ __launch_bounds__(256) void copy_kernel(float* __restrict__ dst,
                                                   const float* __restrict__ src) {
  const size_t i = ((size_t)blockIdx.x * 256 + threadIdx.x) * 4;
  *(float4*)&dst[i] = *(const float4*)&src[i];
}

// ---------------- launch ----------------
extern "C" void kernel_launch(void* const* d_in, const int* in_sizes, int n_in,
                              void* d_out, int out_size, void* d_ws, size_t ws_size,
                              hipStream_t stream) {
  const int*   bytes    = (const int*)d_in[0];
  const float* emb      = (const float*)d_in[1];
  const float* alpha    = (const float*)d_in[2];
  const float* enc_inw  = (const float*)d_in[3];
  const float* enc_inb  = (const float*)d_in[4];
  const float* enc_ow   = (const float*)d_in[5];
  const float* enc_ob   = (const float*)d_in[6];
  const float* enc_w1   = (const float*)d_in[7];
  const float* enc_b1   = (const float*)d_in[8];
  const float* enc_w2   = (const float*)d_in[9];
  const float* enc_b2   = (const float*)d_in[10];
  const float* enc_ln1w = (const float*)d_in[11];
  const float* enc_ln1b = (const float*)d_in[12];
  const float* enc_ln2w = (const float*)d_in[13];
  const float* enc_ln2b = (const float*)d_in[14];
  const float* dec_sa_inw = (const float*)d_in[15];
  const float* dec_sa_inb = (const float*)d_in[16];
  const float* dec_sa_ow  = (const float*)d_in[17];
  const float* dec_sa_ob  = (const float*)d_in[18];
  const float* dec_ca_inw = (const float*)d_in[19];
  const float* dec_ca_inb = (const float*)d_in[20];
  const float* dec_ca_ow  = (const float*)d_in[21];
  const float* dec_ca_ob  = (const float*)d_in[22];
  const float* dec_w1   = (const float*)d_in[23];
  const float* dec_b1   = (const float*)d_in[24];
  const float* dec_w2   = (const float*)d_in[25];
  const float* dec_b2   = (const float*)d_in[26];
  const float* dec_ln1w = (const float*)d_in[27];
  const float* dec_ln1b = (const float*)d_in[28];
  const float* dec_ln2w = (const float*)d_in[29];
  const float* dec_ln2b = (const float*)d_in[30];
  const float* dec_ln3w = (const float*)d_in[31];
  const float* dec_ln3b = (const float*)d_in[32];
  const float* out_w    = (const float*)d_in[33];
  const float* out_b    = (const float*)d_in[34];

  float* ws    = (float*)d_ws;
  float* x     = ws;                              // P*D
  float* enc   = x + (size_t)PP * DD;             // P*D
  float* tok   = enc + (size_t)PP * DD;           // P*D
  float* qkv   = tok + (size_t)PP * DD;           // P*3D
  float* attno = qkv + (size_t)PP * 3 * DD;       // P*D
  float* ffh   = attno + (size_t)PP * DD;         // P*DFF
  float* tmp   = ffh + (size_t)PP * DFF_;         // P*D

  const dim3 b256(256);
  const dim3 gQKV(3 * DD / 64, PP / 64);
  const dim3 gDD(DD / 64, PP / 64);
  const dim3 gFF1(DFF_ / 64, PP / 64);
  const dim3 gKV(2 * DD / 64, PP / 64);
  const dim3 gOUT(VV / 64, PP / 64);
  const dim3 gFA(PP / 32, HN);

  embed_mean_kernel<<<PP, b256, 0, stream>>>(bytes, emb, x, tok);

  // ---------------- encoder ----------------
  for (int l = 0; l < LL; ++l) {
    const float* inw = enc_inw + (size_t)l * 3 * DD * DD;
    const float* inb = enc_inb + (size_t)l * 3 * DD;
    const float* ow  = enc_ow  + (size_t)l * DD * DD;
    const float* ob  = enc_ob  + (size_t)l * DD;
    const float* w1  = enc_w1  + (size_t)l * DFF_ * DD;
    const float* b1  = enc_b1  + (size_t)l * DFF_;
    const float* w2  = enc_w2  + (size_t)l * DD * DFF_;
    const float* b2  = enc_b2  + (size_t)l * DD;

    gemm_bias_kernel<0><<<gQKV, b256, 0, stream>>>(x, DD, inw, DD, inb, qkv, 3 * DD, PP, 3 * DD, DD);
    flash_attn_kernel<<<gFA, b256, 0, stream>>>(qkv, attno);
    gemm_bias_kernel<0><<<gDD, b256, 0, stream>>>(attno, DD, ow, DD, ob, tmp, DD, PP, DD, DD);
    ln_residual_kernel<<<PP / 4, b256, 0, stream>>>(x, tmp, enc_ln1w + (size_t)l * DD, enc_ln1b + (size_t)l * DD, x);
    gemm_bias_kernel<1><<<gFF1, b256, 0, stream>>>(x, DD, w1, DD, b1, ffh, DFF_, PP, DFF_, DD);
    gemm_bias_kernel<0><<<gDD, b256, 0, stream>>>(ffh, DFF_, w2, DFF_, b2, tmp, DD, PP, DD, DFF_);
    ln_residual_kernel<<<PP / 4, b256, 0, stream>>>(x, tmp, enc_ln2w + (size_t)l * DD, enc_ln2b + (size_t)l * DD, x);
  }

  copy_kernel<<<(PP * DD / 4) / 256, b256, 0, stream>>>(enc, x);
  gate_mix_kernel<<<PP / 4, b256, 0, stream>>>(enc, tok, alpha, x);

  // ---------------- decoder ----------------
  for (int l = 0; l < LL; ++l) {
    const float* sa_wv = dec_sa_inw + (size_t)l * 3 * DD * DD + (size_t)2 * DD * DD;
    const float* sa_bv = dec_sa_inb + (size_t)l * 3 * DD + 2 * DD;
    const float* sa_ow = dec_sa_ow + (size_t)l * DD * DD;
    const float* sa_ob = dec_sa_ob + (size_t)l * DD;
    const float* ca_inw = dec_ca_inw + (size_t)l * 3 * DD * DD;
    const float* ca_inb = dec_ca_inb + (size_t)l * 3 * DD;
    const float* ca_ow  = dec_ca_ow + (size_t)l * DD * DD;
    const float* ca_ob  = dec_ca_ob + (size_t)l * DD;
    const float* w1 = dec_w1 + (size_t)l * DFF_ * DD;
    const float* b1 = dec_b1 + (size_t)l * DFF_;
    const float* w2 = dec_w2 + (size_t)l * DD * DFF_;
    const float* b2 = dec_b2 + (size_t)l * DD;

    // self-"attention" (value path only)
    gemm_bias_kernel<0><<<gDD, b256, 0, stream>>>(x, DD, sa_wv, DD, sa_bv, tmp, DD, PP, DD, DD);
    gemm_bias_kernel<0><<<gDD, b256, 0, stream>>>(tmp, DD, sa_ow, DD, sa_ob, attno, DD, PP, DD, DD);
    ln_residual_kernel<<<PP / 4, b256, 0, stream>>>(x, attno, dec_ln1w + (size_t)l * DD, dec_ln1b + (size_t)l * DD, x);

    // cross-attention: q from x, k/v from encoded
    gemm_bias_kernel<0><<<gDD, b256, 0, stream>>>(x, DD, ca_inw, DD, ca_inb, qkv, 3 * DD, PP, DD, DD);
    gemm_bias_kernel<0><<<gKV, b256, 0, stream>>>(enc, DD, ca_inw + (size_t)DD * DD, DD, ca_inb + DD, qkv + DD, 3 * DD, PP, 2 * DD, DD);
    flash_attn_kernel<<<gFA, b256, 0, stream>>>(qkv, attno);
    gemm_bias_kernel<0><<<gDD, b256, 0, stream>>>(attno, DD, ca_ow, DD, ca_ob, tmp, DD, PP, DD, DD);
    ln_residual_kernel<<<PP / 4, b256, 0, stream>>>(x, tmp, dec_ln2w + (size_t)l * DD, dec_ln2b + (size_t)l * DD, x);

    // FFN
    gemm_bias_kernel<1><<<gFF1, b256, 0, stream>>>(x, DD, w1, DD, b1, ffh, DFF_, PP, DFF_, DD);
    gemm_bias_kernel<0><<<gDD, b256, 0, stream>>>(ffh, DFF_, w2, DFF_, b2, tmp, DD, PP, DD, DFF_);
    ln_residual_kernel<<<PP / 4, b256, 0, stream>>>(x, tmp, dec_ln3w + (size_t)l * DD, dec_ln3b + (size_t)l * DD, x);
  }

  // final projection: (P x V)
  gemm_bias_kernel<0><<<gOUT, b256, 0, stream>>>(x, DD, out_w, DD, out_b, (float*)d_out, VV, PP, VV, DD);
}

// Round 2
// 2899.127 us; speedup vs baseline: 1.9874x; 1.9874x over previous
//
#include <hip/hip_runtime.h>
#include <hip/hip_bf16.h>
#include <math.h>

#define DD   512
#define HN   8
#define DHD  64
#define LL   6
#define DFF_ 2048
#define VV   256
#define KB_  5
#define PP   2048
#define EPS_ 1e-5f
#define TAU_ 0.1f

typedef __attribute__((ext_vector_type(8))) short bf16x8;
typedef __attribute__((ext_vector_type(4))) float f32x4;

// ---------------- helpers ----------------
__device__ __forceinline__ float wave_sum(float v) {
#pragma unroll
  for (int m = 32; m >= 1; m >>= 1) v += __shfl_xor(v, m, 64);
  return v;
}

__device__ __forceinline__ unsigned short f2bf(float f) {
  unsigned u = __float_as_uint(f);
  u += 0x7FFF + ((u >> 16) & 1);   // RNE
  return (unsigned short)(u >> 16);
}

__device__ __forceinline__ bf16x8 cvt8(float4 a, float4 b) {
  bf16x8 v;
  v[0] = (short)f2bf(a.x); v[1] = (short)f2bf(a.y);
  v[2] = (short)f2bf(a.z); v[3] = (short)f2bf(a.w);
  v[4] = (short)f2bf(b.x); v[5] = (short)f2bf(b.y);
  v[6] = (short)f2bf(b.z); v[7] = (short)f2bf(b.w);
  return v;
}

// ---------------- embedding ----------------
__global__ __launch_bounds__(256) void embed_mean_kernel(const int* __restrict__ bytes,
                                                         const float* __restrict__ emb,
                                                         float* __restrict__ x,
                                                         float* __restrict__ tok) {
  const int p = blockIdx.x;
  const int d = threadIdx.x * 2;
  float a0 = 0.f, a1 = 0.f;
  int last = 0;
#pragma unroll
  for (int k = 0; k < KB_; ++k) {
    const int idx = bytes[p * KB_ + k];
    last = idx;
    const float* e = emb + (size_t)idx * DD + d;
    a0 += e[0]; a1 += e[1];
  }
  x[(size_t)p * DD + d]     = a0 * 0.2f;
  x[(size_t)p * DD + d + 1] = a1 * 0.2f;
  const float* e = emb + (size_t)last * DD + d;
  tok[(size_t)p * DD + d]     = e[0];
  tok[(size_t)p * DD + d + 1] = e[1];
}

// ---------------- MFMA GEMM: C[M x N] = A[M x Kd] @ W[N x Kd]^T + bias ----------------
// A, W fp32 in global (K-contiguous); converted to bf16 during LDS staging.
// fragment layout (gfx950, verified): A/B lane l: row/col = l&15, k = (l>>4)*8 + j
// C/D lane l: col = l&15, row = (l>>4)*4 + reg
template <int BM, int BN, int RELU>
__global__ __launch_bounds__(256) void gemm_mfma_kernel(
    const float* __restrict__ A, int lda,
    const float* __restrict__ W, int ldw,
    const float* __restrict__ bias,
    float* __restrict__ C, int ldc, int Kd) {
  constexpr int LS = 40;  // bf16 stride: 80B = 20 banks -> even 32-bank spread for b128 frag reads
  __shared__ short As[BM * LS];
  __shared__ short Bs[BN * LS];
  constexpr int WM = BM / 2, WN = BN / 2;
  constexpr int MF = WM / 16, NF = WN / 16;
  const int tid = (int)threadIdx.x;
  const int lane = tid & 63;
  const int wid = tid >> 6;
  const int wm = (wid >> 1) * WM;
  const int wn = (wid & 1) * WN;
  const int bm = blockIdx.y * BM;
  const int bn = blockIdx.x * BN;
  const int sr = tid >> 2;          // staging row 0..63
  const int sc = (tid & 3) * 8;     // staging col 0,8,16,24
  const int fr = lane & 15;
  const int kg = (lane >> 4) * 8;

  f32x4 acc[MF][NF];
#pragma unroll
  for (int i = 0; i < MF; ++i)
#pragma unroll
    for (int j = 0; j < NF; ++j) acc[i][j] = (f32x4){0.f, 0.f, 0.f, 0.f};

  for (int k0 = 0; k0 < Kd; k0 += 32) {
    __syncthreads();
#pragma unroll
    for (int p = 0; p < BM; p += 64) {
      const float* src = A + (size_t)(bm + p + sr) * lda + k0 + sc;
      const float4 x0 = *(const float4*)src;
      const float4 x1 = *(const float4*)(src + 4);
      *(bf16x8*)&As[(p + sr) * LS + sc] = cvt8(x0, x1);
    }
#pragma unroll
    for (int p = 0; p < BN; p += 64) {
      const float* src = W + (size_t)(bn + p + sr) * ldw + k0 + sc;
      const float4 x0 = *(const float4*)src;
      const float4 x1 = *(const float4*)(src + 4);
      *(bf16x8*)&Bs[(p + sr) * LS + sc] = cvt8(x0, x1);
    }
    __syncthreads();
    bf16x8 af[MF], bfr[NF];
#pragma unroll
    for (int i = 0; i < MF; ++i)
      af[i] = *(const bf16x8*)&As[(wm + i * 16 + fr) * LS + kg];
#pragma unroll
    for (int j = 0; j < NF; ++j)
      bfr[j] = *(const bf16x8*)&Bs[(wn + j * 16 + fr) * LS + kg];
#pragma unroll
    for (int i = 0; i < MF; ++i)
#pragma unroll
      for (int j = 0; j < NF; ++j)
        acc[i][j] = __builtin_amdgcn_mfma_f32_16x16x32_bf16(af[i], bfr[j], acc[i][j], 0, 0, 0);
  }

  const int cr = (lane >> 4) * 4;
#pragma unroll
  for (int j = 0; j < NF; ++j) {
    const int col = bn + wn + j * 16 + fr;
    const float bb = bias[col];
#pragma unroll
    for (int i = 0; i < MF; ++i) {
#pragma unroll
      for (int r = 0; r < 4; ++r) {
        float v = acc[i][j][r] + bb;
        if (RELU) v = fmaxf(v, 0.f);
        C[(size_t)(bm + wm + i * 16 + cr + r) * ldc + col] = v;
      }
    }
  }
}

// ---------------- MFMA flash attention ----------------
// qkv: P x 3D fp32 (q at h*64, k at D+h*64, v at 2D+h*64). out: P x D fp32.
// block: (q-tile of 64, head). 4 waves, wave w owns q rows [w*16, w*16+16).
__global__ __launch_bounds__(256) void flash_attn_mfma_kernel(const float* __restrict__ qkv,
                                                              float* __restrict__ out) {
  constexpr int LS = 72;  // bf16 stride: 144B = 36 banks -> even 32-bank spread
  __shared__ short Ks[64 * LS];
  __shared__ short Vt[64 * LS];  // transposed: row = d, col = key
  __shared__ short Ps[64 * LS];
  const int h = blockIdx.y;
  const int q0 = blockIdx.x * 64;
  const int tid = (int)threadIdx.x;
  const int lane = tid & 63;
  const int wid = tid >> 6;
  const int fr = lane & 15;
  const int kg = (lane >> 4) * 8;

  // Q fragments straight to registers (A-operand: m = fr, k(d) = kg+j [+32])
  bf16x8 qf[2];
  {
    const float* src = qkv + (size_t)(q0 + wid * 16 + fr) * (3 * DD) + h * DHD + kg;
#pragma unroll
    for (int kk = 0; kk < 2; ++kk) {
      const float4 a = *(const float4*)(src + kk * 32);
      const float4 b = *(const float4*)(src + kk * 32 + 4);
      qf[kk] = cvt8(a, b);
    }
  }

  f32x4 acc_o[4];
#pragma unroll
  for (int df = 0; df < 4; ++df) acc_o[df] = (f32x4){0.f, 0.f, 0.f, 0.f};
  float mreg[4], lsum[4];
#pragma unroll
  for (int i = 0; i < 4; ++i) { mreg[i] = -INFINITY; lsum[i] = 0.f; }

  const int skr = tid >> 2;            // K stage: row 0..63
  const int skc = (tid & 3) * 16;      // K stage: col 0,16,32,48
  const int svk = tid & 63;            // V stage: key
  const int svd = (tid >> 6) * 16;     // V stage: d0

  for (int k0 = 0; k0 < PP; k0 += 64) {
    __syncthreads();
    {
      const float* ksrc = qkv + (size_t)(k0 + skr) * (3 * DD) + DD + h * DHD + skc;
      const float4 a0 = *(const float4*)ksrc;
      const float4 a1 = *(const float4*)(ksrc + 4);
      const float4 a2 = *(const float4*)(ksrc + 8);
      const float4 a3 = *(const float4*)(ksrc + 12);
      *(bf16x8*)&Ks[skr * LS + skc]     = cvt8(a0, a1);
      *(bf16x8*)&Ks[skr * LS + skc + 8] = cvt8(a2, a3);
      const float* vsrc = qkv + (size_t)(k0 + svk) * (3 * DD) + 2 * DD + h * DHD + svd;
      float vv[16];
      *(float4*)&vv[0]  = *(const float4*)vsrc;
      *(float4*)&vv[4]  = *(const float4*)(vsrc + 4);
      *(float4*)&vv[8]  = *(const float4*)(vsrc + 8);
      *(float4*)&vv[12] = *(const float4*)(vsrc + 12);
#pragma unroll
      for (int j = 0; j < 16; ++j) Vt[(svd + j) * LS + svk] = (short)f2bf(vv[j]);
    }
    __syncthreads();

    // QK^T: S frag nf covers keys nf*16 + fr; reg i -> query (lane>>4)*4 + i
    f32x4 s[4];
#pragma unroll
    for (int nf = 0; nf < 4; ++nf) s[nf] = (f32x4){0.f, 0.f, 0.f, 0.f};
#pragma unroll
    for (int nf = 0; nf < 4; ++nf) {
      const bf16x8 kf0 = *(const bf16x8*)&Ks[(nf * 16 + fr) * LS + kg];
      const bf16x8 kf1 = *(const bf16x8*)&Ks[(nf * 16 + fr) * LS + kg + 32];
      s[nf] = __builtin_amdgcn_mfma_f32_16x16x32_bf16(qf[0], kf0, s[nf], 0, 0, 0);
      s[nf] = __builtin_amdgcn_mfma_f32_16x16x32_bf16(qf[1], kf1, s[nf], 0, 0, 0);
    }

    // online softmax (per reg i = one query row; reduce over 16 lanes = 64 keys)
    float corr[4], pv[4][4];
#pragma unroll
    for (int i = 0; i < 4; ++i) {
      float mx = fmaxf(fmaxf(s[0][i], s[1][i]), fmaxf(s[2][i], s[3][i])) * 0.125f;
#pragma unroll
      for (int t = 1; t < 16; t <<= 1) mx = fmaxf(mx, __shfl_xor(mx, t, 64));
      const float mn = fmaxf(mreg[i], mx);
      corr[i] = __expf(mreg[i] - mn);
      mreg[i] = mn;
      float sum = 0.f;
#pragma unroll
      for (int nf = 0; nf < 4; ++nf) {
        pv[nf][i] = __expf(s[nf][i] * 0.125f - mn);
        sum += pv[nf][i];
      }
#pragma unroll
      for (int t = 1; t < 16; t <<= 1) sum += __shfl_xor(sum, t, 64);
      lsum[i] = lsum[i] * corr[i] + sum;
    }
#pragma unroll
    for (int df = 0; df < 4; ++df) {
      acc_o[df][0] *= corr[0]; acc_o[df][1] *= corr[1];
      acc_o[df][2] *= corr[2]; acc_o[df][3] *= corr[3];
    }

    // P -> LDS (bf16), own wave's 16-row band only
    const int pr = wid * 16 + (lane >> 4) * 4;
#pragma unroll
    for (int nf = 0; nf < 4; ++nf)
#pragma unroll
      for (int i = 0; i < 4; ++i)
        Ps[(pr + i) * LS + nf * 16 + fr] = (short)f2bf(pv[nf][i]);
    asm volatile("s_waitcnt lgkmcnt(0)" ::: "memory");

    // PV: A = P (m=q, k=key), B = Vt (k=key, n=d)
    const bf16x8 pa0 = *(const bf16x8*)&Ps[(wid * 16 + fr) * LS + kg];
    const bf16x8 pa1 = *(const bf16x8*)&Ps[(wid * 16 + fr) * LS + kg + 32];
#pragma unroll
    for (int df = 0; df < 4; ++df) {
      const bf16x8 vb0 = *(const bf16x8*)&Vt[(df * 16 + fr) * LS + kg];
      const bf16x8 vb1 = *(const bf16x8*)&Vt[(df * 16 + fr) * LS + kg + 32];
      acc_o[df] = __builtin_amdgcn_mfma_f32_16x16x32_bf16(pa0, vb0, acc_o[df], 0, 0, 0);
      acc_o[df] = __builtin_amdgcn_mfma_f32_16x16x32_bf16(pa1, vb1, acc_o[df], 0, 0, 0);
    }
  }

  float inv[4];
#pragma unroll
  for (int i = 0; i < 4; ++i) inv[i] = 1.f / lsum[i];
  const int orow = q0 + wid * 16 + (lane >> 4) * 4;
#pragma unroll
  for (int df = 0; df < 4; ++df)
#pragma unroll
    for (int i = 0; i < 4; ++i)
      out[(size_t)(orow + i) * DD + h * DHD + df * 16 + fr] = acc_o[df][i] * inv[i];
}

// ---------------- LN(x + res) * w + b ----------------
__global__ __launch_bounds__(256) void ln_residual_kernel(const float* __restrict__ xin,
                                                          const float* __restrict__ res,
                                                          const float* __restrict__ w,
                                                          const float* __restrict__ b,
                                                          float* __restrict__ out) {
  const int row = blockIdx.x * 4 + (threadIdx.x >> 6);
  const int lane = threadIdx.x & 63;
  const float* xr = xin + (size_t)row * DD + lane * 8;
  const float* rr = res + (size_t)row * DD + lane * 8;
  float v[8];
  {
    const float4 a0 = *(const float4*)xr;
    const float4 a1 = *(const float4*)(xr + 4);
    const float4 r0 = *(const float4*)rr;
    const float4 r1 = *(const float4*)(rr + 4);
    v[0] = a0.x + r0.x; v[1] = a0.y + r0.y; v[2] = a0.z + r0.z; v[3] = a0.w + r0.w;
    v[4] = a1.x + r1.x; v[5] = a1.y + r1.y; v[6] = a1.z + r1.z; v[7] = a1.w + r1.w;
  }
  float sum = 0.f;
#pragma unroll
  for (int j = 0; j < 8; ++j) sum += v[j];
  sum = wave_sum(sum);
  const float mean = sum * (1.f / DD);
  float sq = 0.f;
#pragma unroll
  for (int j = 0; j < 8; ++j) { const float d = v[j] - mean; sq += d * d; }
  sq = wave_sum(sq);
  const float rstd = rsqrtf(sq * (1.f / DD) + EPS_);
  const float* wp = w + lane * 8;
  const float* bp = b + lane * 8;
  float* op = out + (size_t)row * DD + lane * 8;
  float4 o0, o1;
  o0.x = (v[0] - mean) * rstd * wp[0] + bp[0];
  o0.y = (v[1] - mean) * rstd * wp[1] + bp[1];
  o0.z = (v[2] - mean) * rstd * wp[2] + bp[2];
  o0.w = (v[3] - mean) * rstd * wp[3] + bp[3];
  o1.x = (v[4] - mean) * rstd * wp[4] + bp[4];
  o1.y = (v[5] - mean) * rstd * wp[5] + bp[5];
  o1.z = (v[6] - mean) * rstd * wp[6] + bp[6];
  o1.w = (v[7] - mean) * rstd * wp[7] + bp[7];
  *(float4*)op = o0;
  *(float4*)(op + 4) = o1;
}

// ---------------- gate + mix ----------------
__global__ __launch_bounds__(256) void gate_mix_kernel(const float* __restrict__ enc,
                                                       const float* __restrict__ tok,
                                                       const float* __restrict__ alpha_p,
                                                       float* __restrict__ x) {
  const int row = blockIdx.x * 4 + (threadIdx.x >> 6);
  const int lane = threadIdx.x & 63;
  const float* er = enc + (size_t)row * DD + lane * 8;
  const float* tr = tok + (size_t)row * DD + lane * 8;
  float e[8], t[8];
  {
    const float4 a0 = *(const float4*)er;
    const float4 a1 = *(const float4*)(er + 4);
    const float4 b0 = *(const float4*)tr;
    const float4 b1 = *(const float4*)(tr + 4);
    e[0] = a0.x; e[1] = a0.y; e[2] = a0.z; e[3] = a0.w;
    e[4] = a1.x; e[5] = a1.y; e[6] = a1.z; e[7] = a1.w;
    t[0] = b0.x; t[1] = b0.y; t[2] = b0.z; t[3] = b0.w;
    t[4] = b1.x; t[5] = b1.y; t[6] = b1.z; t[7] = b1.w;
  }
  float sq = 0.f;
#pragma unroll
  for (int j = 0; j < 8; ++j) sq += e[j] * e[j];
  sq = wave_sum(sq);
  const bool gate = sq > TAU_ * TAU_;
  const float a = *alpha_p;
  float* op = x + (size_t)row * DD + lane * 8;
  float o[8];
#pragma unroll
  for (int j = 0; j < 8; ++j) o[j] = gate ? (a * e[j] + (1.f - a) * t[j]) : t[j];
  *(float4*)op = *(float4*)&o[0];
  *(float4*)(op + 4) = *(float4*)&o[4];
}

// ---------------- copy ----------------
__global__ __launch_bounds__(256) void copy_kernel(float* __restrict__ dst,
                                                   const float* __restrict__ src) {
  const size_t i = ((size_t)blockIdx.x * 256 + threadIdx.x) * 4;
  *(float4*)&dst[i] = *(const float4*)&src[i];
}

// ---------------- launch ----------------
extern "C" void kernel_launch(void* const* d_in, const int* in_sizes, int n_in,
                              void* d_out, int out_size, void* d_ws, size_t ws_size,
                              hipStream_t stream) {
  const int*   bytes    = (const int*)d_in[0];
  const float* emb      = (const float*)d_in[1];
  const float* alpha    = (const float*)d_in[2];
  const float* enc_inw  = (const float*)d_in[3];
  const float* enc_inb  = (const float*)d_in[4];
  const float* enc_ow   = (const float*)d_in[5];
  const float* enc_ob   = (const float*)d_in[6];
  const float* enc_w1   = (const float*)d_in[7];
  const float* enc_b1   = (const float*)d_in[8];
  const float* enc_w2   = (const float*)d_in[9];
  const float* enc_b2   = (const float*)d_in[10];
  const float* enc_ln1w = (const float*)d_in[11];
  const float* enc_ln1b = (const float*)d_in[12];
  const float* enc_ln2w = (const float*)d_in[13];
  const float* enc_ln2b = (const float*)d_in[14];
  const float* dec_sa_inw = (const float*)d_in[15];
  const float* dec_sa_inb = (const float*)d_in[16];
  const float* dec_sa_ow  = (const float*)d_in[17];
  const float* dec_sa_ob  = (const float*)d_in[18];
  const float* dec_ca_inw = (const float*)d_in[19];
  const float* dec_ca_inb = (const float*)d_in[20];
  const float* dec_ca_ow  = (const float*)d_in[21];
  const float* dec_ca_ob  = (const float*)d_in[22];
  const float* dec_w1   = (const float*)d_in[23];
  const float* dec_b1   = (const float*)d_in[24];
  const float* dec_w2   = (const float*)d_in[25];
  const float* dec_b2   = (const float*)d_in[26];
  const float* dec_ln1w = (const float*)d_in[27];
  const float* dec_ln1b = (const float*)d_in[28];
  const float* dec_ln2w = (const float*)d_in[29];
  const float* dec_ln2b = (const float*)d_in[30];
  const float* dec_ln3w = (const float*)d_in[31];
  const float* dec_ln3b = (const float*)d_in[32];
  const float* out_w    = (const float*)d_in[33];
  const float* out_b    = (const float*)d_in[34];

  float* ws    = (float*)d_ws;
  float* x     = ws;
  float* enc   = x + (size_t)PP * DD;
  float* tok   = enc + (size_t)PP * DD;
  float* qkv   = tok + (size_t)PP * DD;
  float* attno = qkv + (size_t)PP * 3 * DD;
  float* ffh   = attno + (size_t)PP * DD;
  float* tmp   = ffh + (size_t)PP * DFF_;

  const dim3 b256(256);
  const dim3 gFA(PP / 64, HN);
  const dim3 gQKV(3 * DD / 128, PP / 128);     // 12 x 16
  const dim3 gFF1(DFF_ / 128, PP / 128);       // 16 x 16
  const dim3 gDD64(DD / 64, PP / 64);          // 8 x 32
  const dim3 gKV64(2 * DD / 64, PP / 64);      // 16 x 32
  const dim3 gOUT(VV / 64, PP / 64);           // 4 x 32

  embed_mean_kernel<<<PP, b256, 0, stream>>>(bytes, emb, x, tok);

  // ---------------- encoder ----------------
  for (int l = 0; l < LL; ++l) {
    const float* inw = enc_inw + (size_t)l * 3 * DD * DD;
    const float* inb = enc_inb + (size_t)l * 3 * DD;
    const float* ow  = enc_ow  + (size_t)l * DD * DD;
    const float* ob  = enc_ob  + (size_t)l * DD;
    const float* w1  = enc_w1  + (size_t)l * DFF_ * DD;
    const float* b1  = enc_b1  + (size_t)l * DFF_;
    const float* w2  = enc_w2  + (size_t)l * DD * DFF_;
    const float* b2  = enc_b2  + (size_t)l * DD;

    gemm_mfma_kernel<128, 128, 0><<<gQKV, b256, 0, stream>>>(x, DD, inw, DD, inb, qkv, 3 * DD, DD);
    flash_attn_mfma_kernel<<<gFA, b256, 0, stream>>>(qkv, attno);
    gemm_mfma_kernel<64, 64, 0><<<gDD64, b256, 0, stream>>>(attno, DD, ow, DD, ob, tmp, DD, DD);
    ln_residual_kernel<<<PP / 4, b256, 0, stream>>>(x, tmp, enc_ln1w + (size_t)l * DD, enc_ln1b + (size_t)l * DD, x);
    gemm_mfma_kernel<128, 128, 1><<<gFF1, b256, 0, stream>>>(x, DD, w1, DD, b1, ffh, DFF_, DD);
    gemm_mfma_kernel<64, 64, 0><<<gDD64, b256, 0, stream>>>(ffh, DFF_, w2, DFF_, b2, tmp, DD, DFF_);
    ln_residual_kernel<<<PP / 4, b256, 0, stream>>>(x, tmp, enc_ln2w + (size_t)l * DD, enc_ln2b + (size_t)l * DD, x);
  }

  copy_kernel<<<(PP * DD / 4) / 256, b256, 0, stream>>>(enc, x);
  gate_mix_kernel<<<PP / 4, b256, 0, stream>>>(enc, tok, alpha, x);

  // ---------------- decoder ----------------
  for (int l = 0; l < LL; ++l) {
    const float* sa_wv = dec_sa_inw + (size_t)l * 3 * DD * DD + (size_t)2 * DD * DD;
    const float* sa_bv = dec_sa_inb + (size_t)l * 3 * DD + 2 * DD;
    const float* sa_ow = dec_sa_ow + (size_t)l * DD * DD;
    const float* sa_ob = dec_sa_ob + (size_t)l * DD;
    const float* ca_inw = dec_ca_inw + (size_t)l * 3 * DD * DD;
    const float* ca_inb = dec_ca_inb + (size_t)l * 3 * DD;
    const float* ca_ow  = dec_ca_ow + (size_t)l * DD * DD;
    const float* ca_ob  = dec_ca_ob + (size_t)l * DD;
    const float* w1 = dec_w1 + (size_t)l * DFF_ * DD;
    const float* b1 = dec_b1 + (size_t)l * DFF_;
    const float* w2 = dec_w2 + (size_t)l * DD * DFF_;
    const float* b2 = dec_b2 + (size_t)l * DD;

    gemm_mfma_kernel<64, 64, 0><<<gDD64, b256, 0, stream>>>(x, DD, sa_wv, DD, sa_bv, tmp, DD, DD);
    gemm_mfma_kernel<64, 64, 0><<<gDD64, b256, 0, stream>>>(tmp, DD, sa_ow, DD, sa_ob, attno, DD, DD);
    ln_residual_kernel<<<PP / 4, b256, 0, stream>>>(x, attno, dec_ln1w + (size_t)l * DD, dec_ln1b + (size_t)l * DD, x);

    gemm_mfma_kernel<64, 64, 0><<<gDD64, b256, 0, stream>>>(x, DD, ca_inw, DD, ca_inb, qkv, 3 * DD, DD);
    gemm_mfma_kernel<64, 64, 0><<<gKV64, b256, 0, stream>>>(enc, DD, ca_inw + (size_t)DD * DD, DD, ca_inb + DD, qkv + DD, 3 * DD, DD);
    flash_attn_mfma_kernel<<<gFA, b256, 0, stream>>>(qkv, attno);
    gemm_mfma_kernel<64, 64, 0><<<gDD64, b256, 0, stream>>>(attno, DD, ca_ow, DD, ca_ob, tmp, DD, DD);
    ln_residual_kernel<<<PP / 4, b256, 0, stream>>>(x, tmp, dec_ln2w + (size_t)l * DD, dec_ln2b + (size_t)l * DD, x);

    gemm_mfma_kernel<128, 128, 1><<<gFF1, b256, 0, stream>>>(x, DD, w1, DD, b1, ffh, DFF_, DD);
    gemm_mfma_kernel<64, 64, 0><<<gDD64, b256, 0, stream>>>(ffh, DFF_, w2, DFF_, b2, tmp, DD, DFF_);
    ln_residual_kernel<<<PP / 4, b256, 0, stream>>>(x, tmp, dec_ln3w + (size_t)l * DD, dec_ln3b + (size_t)l * DD, x);
  }

  gemm_mfma_kernel<64, 64, 0><<<gOUT, b256, 0, stream>>>(x, DD, out_w, DD, out_b, (float*)d_out, VV, DD);
}

// Round 3
// 1656.806 us; speedup vs baseline: 3.4776x; 1.7498x over previous
//
#include <hip/hip_runtime.h>
#include <hip/hip_bf16.h>
#include <math.h>

#define DD   512
#define HN   8
#define DHD  64
#define LL   6
#define DFF_ 2048
#define VV   256
#define KB_  5
#define PP   2048
#define EPS_ 1e-5f
#define TAU_ 0.1f
#define NS   4          // KV splits for flash attention
#define KVS  (PP / NS)  // 512 keys per split

typedef __attribute__((ext_vector_type(8))) short bf16x8;
typedef __attribute__((ext_vector_type(4))) float f32x4;

// ---------------- helpers ----------------
__device__ __forceinline__ float wave_sum(float v) {
#pragma unroll
  for (int m = 32; m >= 1; m >>= 1) v += __shfl_xor(v, m, 64);
  return v;
}

__device__ __forceinline__ unsigned short f2bf(float f) {
  unsigned u = __float_as_uint(f);
  u += 0x7FFF + ((u >> 16) & 1);   // RNE
  return (unsigned short)(u >> 16);
}

__device__ __forceinline__ bf16x8 cvt8(float4 a, float4 b) {
  bf16x8 v;
  v[0] = (short)f2bf(a.x); v[1] = (short)f2bf(a.y);
  v[2] = (short)f2bf(a.z); v[3] = (short)f2bf(a.w);
  v[4] = (short)f2bf(b.x); v[5] = (short)f2bf(b.y);
  v[6] = (short)f2bf(b.z); v[7] = (short)f2bf(b.w);
  return v;
}

// ---------------- batched fp32 -> bf16 convert ----------------
struct CvtSeg { const float* src; short* dst; int n; };
struct CvtArgs { CvtSeg seg[6]; };

__global__ __launch_bounds__(256) void convert_bf16_kernel(CvtArgs a) {
  const CvtSeg sg = a.seg[blockIdx.y];
  const int i = ((int)blockIdx.x * 256 + (int)threadIdx.x) * 8;
  if (i >= sg.n) return;
  const float4 x0 = *(const float4*)(sg.src + i);
  const float4 x1 = *(const float4*)(sg.src + i + 4);
  *(bf16x8*)(sg.dst + i) = cvt8(x0, x1);
}

// ---------------- embedding ----------------
__global__ __launch_bounds__(256) void embed_mean_kernel(const int* __restrict__ bytes,
                                                         const float* __restrict__ emb,
                                                         float* __restrict__ x,
                                                         short* __restrict__ xb,
                                                         float* __restrict__ tok) {
  const int p = blockIdx.x;
  const int d = threadIdx.x * 2;
  float a0 = 0.f, a1 = 0.f;
  int last = 0;
#pragma unroll
  for (int k = 0; k < KB_; ++k) {
    const int idx = bytes[p * KB_ + k];
    last = idx;
    const float* e = emb + (size_t)idx * DD + d;
    a0 += e[0]; a1 += e[1];
  }
  a0 *= 0.2f; a1 *= 0.2f;
  x[(size_t)p * DD + d]     = a0;
  x[(size_t)p * DD + d + 1] = a1;
  xb[(size_t)p * DD + d]     = (short)f2bf(a0);
  xb[(size_t)p * DD + d + 1] = (short)f2bf(a1);
  const float* e = emb + (size_t)last * DD + d;
  tok[(size_t)p * DD + d]     = e[0];
  tok[(size_t)p * DD + d + 1] = e[1];
}

// ---------------- MFMA GEMM (bf16 in, fp32 accum): C = A @ W^T + bias ----------------
// A[M x Kd] bf16, W[N x Kd] bf16, both K-contiguous.
template <int BM, int BN, int RELU, int WF32, int WBF16>
__global__ __launch_bounds__(256) void gemm_mfma_kernel(
    const short* __restrict__ A, int lda,
    const short* __restrict__ W, int ldw,
    const float* __restrict__ bias,
    float* __restrict__ Cf, short* __restrict__ Cb, int ldc, int Kd) {
  __shared__ short As[BM * 32];
  __shared__ short Bs[BN * 32];
  constexpr int WM = BM / 2, WN = BN / 2;
  constexpr int MF = WM / 16, NF = WN / 16;
  const int tid = (int)threadIdx.x;
  const int lane = tid & 63;
  const int wid = tid >> 6;
  const int wm = (wid >> 1) * WM;
  const int wn = (wid & 1) * WN;
  const int bm = blockIdx.y * BM;
  const int bn = blockIdx.x * BN;
  const int sr = tid >> 2;          // staging row 0..63
  const int sc = (tid & 3) * 8;     // staging col 0,8,16,24
  const int fr = lane & 15;
  const int kg = (lane >> 4) * 8;

  f32x4 acc[MF][NF];
#pragma unroll
  for (int i = 0; i < MF; ++i)
#pragma unroll
    for (int j = 0; j < NF; ++j) acc[i][j] = (f32x4){0.f, 0.f, 0.f, 0.f};

  for (int k0 = 0; k0 < Kd; k0 += 32) {
    __syncthreads();
#pragma unroll
    for (int p = 0; p < BM; p += 64)
      *(bf16x8*)&As[(p + sr) * 32 + sc] =
          *(const bf16x8*)&A[(size_t)(bm + p + sr) * lda + k0 + sc];
#pragma unroll
    for (int p = 0; p < BN; p += 64)
      *(bf16x8*)&Bs[(p + sr) * 32 + sc] =
          *(const bf16x8*)&W[(size_t)(bn + p + sr) * ldw + k0 + sc];
    __syncthreads();
    bf16x8 af[MF], bfr[NF];
#pragma unroll
    for (int i = 0; i < MF; ++i)
      af[i] = *(const bf16x8*)&As[(wm + i * 16 + fr) * 32 + kg];
#pragma unroll
    for (int j = 0; j < NF; ++j)
      bfr[j] = *(const bf16x8*)&Bs[(wn + j * 16 + fr) * 32 + kg];
#pragma unroll
    for (int i = 0; i < MF; ++i)
#pragma unroll
      for (int j = 0; j < NF; ++j)
        acc[i][j] = __builtin_amdgcn_mfma_f32_16x16x32_bf16(af[i], bfr[j], acc[i][j], 0, 0, 0);
  }

  const int cr = (lane >> 4) * 4;
#pragma unroll
  for (int j = 0; j < NF; ++j) {
    const int col = bn + wn + j * 16 + fr;
    const float bb = bias[col];
#pragma unroll
    for (int i = 0; i < MF; ++i) {
#pragma unroll
      for (int r = 0; r < 4; ++r) {
        float v = acc[i][j][r] + bb;
        if (RELU) v = fmaxf(v, 0.f);
        const size_t idx = (size_t)(bm + wm + i * 16 + cr + r) * ldc + col;
        if (WF32) Cf[idx] = v;
        if (WBF16) Cb[idx] = (short)f2bf(v);
      }
    }
  }
}

// ---------------- MFMA flash attention with KV split ----------------
// qkvb: P x 3D bf16. Opart: [NS][P][D] fp32 raw. stats: [NS][P][H] float2 (m,l).
__global__ __launch_bounds__(256) void flash_attn_mfma_kernel(const short* __restrict__ qkvb,
                                                              float* __restrict__ Opart,
                                                              float* __restrict__ stats) {
  constexpr int LS = 72;
  __shared__ short Ks[64 * LS];
  __shared__ short Vt[64 * LS];  // transposed: row = d, col = key
  __shared__ short Ps[64 * LS];
  const int h = blockIdx.y;
  const int q0 = blockIdx.x * 64;
  const int sp = blockIdx.z;
  const int tid = (int)threadIdx.x;
  const int lane = tid & 63;
  const int wid = tid >> 6;
  const int fr = lane & 15;
  const int kg = (lane >> 4) * 8;

  // Q fragments to registers (A-operand: m = fr, k(d) = kg+j)
  bf16x8 qf[2];
  {
    const short* src = qkvb + (size_t)(q0 + wid * 16 + fr) * (3 * DD) + h * DHD + kg;
    qf[0] = *(const bf16x8*)src;
    qf[1] = *(const bf16x8*)(src + 32);
  }

  f32x4 acc_o[4];
#pragma unroll
  for (int df = 0; df < 4; ++df) acc_o[df] = (f32x4){0.f, 0.f, 0.f, 0.f};
  float mreg[4], lsum[4];
#pragma unroll
  for (int i = 0; i < 4; ++i) { mreg[i] = -INFINITY; lsum[i] = 0.f; }

  const int sr8 = tid >> 3;          // 0..31
  const int sc8 = (tid & 7) * 8;     // 0..56
  const int vk = tid & 63;           // key
  const int vd = (tid >> 6) * 8;     // d0: 0,8,16,24

  for (int t = 0; t < KVS / 64; ++t) {
    const int k0 = sp * KVS + t * 64;
    __syncthreads();
    {
#pragma unroll
      for (int p = 0; p < 64; p += 32)
        *(bf16x8*)&Ks[(sr8 + p) * LS + sc8] =
            *(const bf16x8*)&qkvb[(size_t)(k0 + sr8 + p) * (3 * DD) + DD + h * DHD + sc8];
#pragma unroll
      for (int p = 0; p < 64; p += 32) {
        const bf16x8 v = *(const bf16x8*)&qkvb[(size_t)(k0 + vk) * (3 * DD) + 2 * DD + h * DHD + vd + p];
#pragma unroll
        for (int j = 0; j < 8; ++j) Vt[(vd + p + j) * LS + vk] = v[j];
      }
    }
    __syncthreads();

    // QK^T
    f32x4 s[4];
#pragma unroll
    for (int nf = 0; nf < 4; ++nf) s[nf] = (f32x4){0.f, 0.f, 0.f, 0.f};
#pragma unroll
    for (int nf = 0; nf < 4; ++nf) {
      const bf16x8 kf0 = *(const bf16x8*)&Ks[(nf * 16 + fr) * LS + kg];
      const bf16x8 kf1 = *(const bf16x8*)&Ks[(nf * 16 + fr) * LS + kg + 32];
      s[nf] = __builtin_amdgcn_mfma_f32_16x16x32_bf16(qf[0], kf0, s[nf], 0, 0, 0);
      s[nf] = __builtin_amdgcn_mfma_f32_16x16x32_bf16(qf[1], kf1, s[nf], 0, 0, 0);
    }

    // online softmax (reg i = one query row)
    float corr[4], pv[4][4];
#pragma unroll
    for (int i = 0; i < 4; ++i) {
      float mx = fmaxf(fmaxf(s[0][i], s[1][i]), fmaxf(s[2][i], s[3][i])) * 0.125f;
#pragma unroll
      for (int tt = 1; tt < 16; tt <<= 1) mx = fmaxf(mx, __shfl_xor(mx, tt, 64));
      const float mn = fmaxf(mreg[i], mx);
      corr[i] = __expf(mreg[i] - mn);
      mreg[i] = mn;
      float sum = 0.f;
#pragma unroll
      for (int nf = 0; nf < 4; ++nf) {
        pv[nf][i] = __expf(s[nf][i] * 0.125f - mn);
        sum += pv[nf][i];
      }
#pragma unroll
      for (int tt = 1; tt < 16; tt <<= 1) sum += __shfl_xor(sum, tt, 64);
      lsum[i] = lsum[i] * corr[i] + sum;
    }
#pragma unroll
    for (int df = 0; df < 4; ++df) {
      acc_o[df][0] *= corr[0]; acc_o[df][1] *= corr[1];
      acc_o[df][2] *= corr[2]; acc_o[df][3] *= corr[3];
    }

    // P -> LDS bf16 (own wave's band)
    const int pr = wid * 16 + (lane >> 4) * 4;
#pragma unroll
    for (int nf = 0; nf < 4; ++nf)
#pragma unroll
      for (int i = 0; i < 4; ++i)
        Ps[(pr + i) * LS + nf * 16 + fr] = (short)f2bf(pv[nf][i]);
    asm volatile("s_waitcnt lgkmcnt(0)" ::: "memory");

    // PV
    const bf16x8 pa0 = *(const bf16x8*)&Ps[(wid * 16 + fr) * LS + kg];
    const bf16x8 pa1 = *(const bf16x8*)&Ps[(wid * 16 + fr) * LS + kg + 32];
#pragma unroll
    for (int df = 0; df < 4; ++df) {
      const bf16x8 vb0 = *(const bf16x8*)&Vt[(df * 16 + fr) * LS + kg];
      const bf16x8 vb1 = *(const bf16x8*)&Vt[(df * 16 + fr) * LS + kg + 32];
      acc_o[df] = __builtin_amdgcn_mfma_f32_16x16x32_bf16(pa0, vb0, acc_o[df], 0, 0, 0);
      acc_o[df] = __builtin_amdgcn_mfma_f32_16x16x32_bf16(pa1, vb1, acc_o[df], 0, 0, 0);
    }
  }

  // raw partial output + stats
  const int g = lane >> 4;
  const int orow = q0 + wid * 16 + g * 4;
#pragma unroll
  for (int df = 0; df < 4; ++df)
#pragma unroll
    for (int i = 0; i < 4; ++i)
      Opart[((size_t)sp * PP + orow + i) * DD + h * DHD + df * 16 + fr] = acc_o[df][i];
  if (fr == 0) {
#pragma unroll
    for (int i = 0; i < 4; ++i) {
      const size_t si = (((size_t)sp * PP + orow + i) * HN + h) * 2;
      stats[si]     = mreg[i];
      stats[si + 1] = lsum[i];
    }
  }
}

// ---------------- combine NS partials -> attno bf16 ----------------
__global__ __launch_bounds__(256) void attn_combine_kernel(const float* __restrict__ Opart,
                                                           const float* __restrict__ stats,
                                                           short* __restrict__ outb) {
  const int row = blockIdx.x;
  const int d = (int)threadIdx.x * 2;
  const int h = d >> 6;
  float m[NS], l[NS];
  float M = -INFINITY;
#pragma unroll
  for (int s = 0; s < NS; ++s) {
    const size_t si = (((size_t)s * PP + row) * HN + h) * 2;
    m[s] = stats[si]; l[s] = stats[si + 1];
    M = fmaxf(M, m[s]);
  }
  float L = 0.f, o0 = 0.f, o1 = 0.f;
#pragma unroll
  for (int s = 0; s < NS; ++s) {
    const float e = __expf(m[s] - M);
    L += l[s] * e;
    const float* op = Opart + ((size_t)s * PP + row) * DD + d;
    o0 += op[0] * e;
    o1 += op[1] * e;
  }
  const float inv = 1.f / L;
  outb[(size_t)row * DD + d]     = (short)f2bf(o0 * inv);
  outb[(size_t)row * DD + d + 1] = (short)f2bf(o1 * inv);
}

// ---------------- LN(x + res) * w + b -> out fp32 + bf16 ----------------
__global__ __launch_bounds__(256) void ln_residual_kernel(const float* __restrict__ xin,
                                                          const float* __restrict__ res,
                                                          const float* __restrict__ w,
                                                          const float* __restrict__ b,
                                                          float* __restrict__ out,
                                                          short* __restrict__ outb) {
  const int row = blockIdx.x * 4 + (threadIdx.x >> 6);
  const int lane = threadIdx.x & 63;
  const float* xr = xin + (size_t)row * DD + lane * 8;
  const float* rr = res + (size_t)row * DD + lane * 8;
  float v[8];
  {
    const float4 a0 = *(const float4*)xr;
    const float4 a1 = *(const float4*)(xr + 4);
    const float4 r0 = *(const float4*)rr;
    const float4 r1 = *(const float4*)(rr + 4);
    v[0] = a0.x + r0.x; v[1] = a0.y + r0.y; v[2] = a0.z + r0.z; v[3] = a0.w + r0.w;
    v[4] = a1.x + r1.x; v[5] = a1.y + r1.y; v[6] = a1.z + r1.z; v[7] = a1.w + r1.w;
  }
  float sum = 0.f;
#pragma unroll
  for (int j = 0; j < 8; ++j) sum += v[j];
  sum = wave_sum(sum);
  const float mean = sum * (1.f / DD);
  float sq = 0.f;
#pragma unroll
  for (int j = 0; j < 8; ++j) { const float dd = v[j] - mean; sq += dd * dd; }
  sq = wave_sum(sq);
  const float rstd = rsqrtf(sq * (1.f / DD) + EPS_);
  const float* wp = w + lane * 8;
  const float* bp = b + lane * 8;
  float o[8];
#pragma unroll
  for (int j = 0; j < 8; ++j) o[j] = (v[j] - mean) * rstd * wp[j] + bp[j];
  float* op = out + (size_t)row * DD + lane * 8;
  *(float4*)op = *(float4*)&o[0];
  *(float4*)(op + 4) = *(float4*)&o[4];
  bf16x8 ob;
#pragma unroll
  for (int j = 0; j < 8; ++j) ob[j] = (short)f2bf(o[j]);
  *(bf16x8*)&outb[(size_t)row * DD + lane * 8] = ob;
}

// ---------------- gate + mix ----------------
__global__ __launch_bounds__(256) void gate_mix_kernel(const float* __restrict__ enc,
                                                       const float* __restrict__ tok,
                                                       const float* __restrict__ alpha_p,
                                                       float* __restrict__ x,
                                                       short* __restrict__ xb) {
  const int row = blockIdx.x * 4 + (threadIdx.x >> 6);
  const int lane = threadIdx.x & 63;
  const float* er = enc + (size_t)row * DD + lane * 8;
  const float* tr = tok + (size_t)row * DD + lane * 8;
  float e[8], t[8];
  {
    const float4 a0 = *(const float4*)er;
    const float4 a1 = *(const float4*)(er + 4);
    const float4 b0 = *(const float4*)tr;
    const float4 b1 = *(const float4*)(tr + 4);
    e[0] = a0.x; e[1] = a0.y; e[2] = a0.z; e[3] = a0.w;
    e[4] = a1.x; e[5] = a1.y; e[6] = a1.z; e[7] = a1.w;
    t[0] = b0.x; t[1] = b0.y; t[2] = b0.z; t[3] = b0.w;
    t[4] = b1.x; t[5] = b1.y; t[6] = b1.z; t[7] = b1.w;
  }
  float sq = 0.f;
#pragma unroll
  for (int j = 0; j < 8; ++j) sq += e[j] * e[j];
  sq = wave_sum(sq);
  const bool gate = sq > TAU_ * TAU_;
  const float a = *alpha_p;
  float o[8];
#pragma unroll
  for (int j = 0; j < 8; ++j) o[j] = gate ? (a * e[j] + (1.f - a) * t[j]) : t[j];
  float* op = x + (size_t)row * DD + lane * 8;
  *(float4*)op = *(float4*)&o[0];
  *(float4*)(op + 4) = *(float4*)&o[4];
  bf16x8 ob;
#pragma unroll
  for (int j = 0; j < 8; ++j) ob[j] = (short)f2bf(o[j]);
  *(bf16x8*)&xb[(size_t)row * DD + lane * 8] = ob;
}

// ---------------- copy x -> enc (fp32 + bf16) ----------------
__global__ __launch_bounds__(256) void copy_dual_kernel(float* __restrict__ dst,
                                                        short* __restrict__ dstb,
                                                        const float* __restrict__ src) {
  const size_t i = ((size_t)blockIdx.x * 256 + threadIdx.x) * 8;
  const float4 a0 = *(const float4*)&src[i];
  const float4 a1 = *(const float4*)&src[i + 4];
  *(float4*)&dst[i] = a0;
  *(float4*)&dst[i + 4] = a1;
  *(bf16x8*)&dstb[i] = cvt8(a0, a1);
}

// ---------------- launch ----------------
extern "C" void kernel_launch(void* const* d_in, const int* in_sizes, int n_in,
                              void* d_out, int out_size, void* d_ws, size_t ws_size,
                              hipStream_t stream) {
  const int*   bytes    = (const int*)d_in[0];
  const float* emb      = (const float*)d_in[1];
  const float* alpha    = (const float*)d_in[2];
  const float* enc_inw  = (const float*)d_in[3];
  const float* enc_inb  = (const float*)d_in[4];
  const float* enc_ow   = (const float*)d_in[5];
  const float* enc_ob   = (const float*)d_in[6];
  const float* enc_w1   = (const float*)d_in[7];
  const float* enc_b1   = (const float*)d_in[8];
  const float* enc_w2   = (const float*)d_in[9];
  const float* enc_b2   = (const float*)d_in[10];
  const float* enc_ln1w = (const float*)d_in[11];
  const float* enc_ln1b = (const float*)d_in[12];
  const float* enc_ln2w = (const float*)d_in[13];
  const float* enc_ln2b = (const float*)d_in[14];
  const float* dec_sa_inw = (const float*)d_in[15];
  const float* dec_sa_inb = (const float*)d_in[16];
  const float* dec_sa_ow  = (const float*)d_in[17];
  const float* dec_sa_ob  = (const float*)d_in[18];
  const float* dec_ca_inw = (const float*)d_in[19];
  const float* dec_ca_inb = (const float*)d_in[20];
  const float* dec_ca_ow  = (const float*)d_in[21];
  const float* dec_ca_ob  = (const float*)d_in[22];
  const float* dec_w1   = (const float*)d_in[23];
  const float* dec_b1   = (const float*)d_in[24];
  const float* dec_w2   = (const float*)d_in[25];
  const float* dec_b2   = (const float*)d_in[26];
  const float* dec_ln1w = (const float*)d_in[27];
  const float* dec_ln1b = (const float*)d_in[28];
  const float* dec_ln2w = (const float*)d_in[29];
  const float* dec_ln2b = (const float*)d_in[30];
  const float* dec_ln3w = (const float*)d_in[31];
  const float* dec_ln3b = (const float*)d_in[32];
  const float* out_w    = (const float*)d_in[33];
  const float* out_b    = (const float*)d_in[34];

  // ---- workspace layout ----
  float* fp = (float*)d_ws;
  float* x     = fp;  fp += (size_t)PP * DD;
  float* enc   = fp;  fp += (size_t)PP * DD;
  float* tok   = fp;  fp += (size_t)PP * DD;
  float* tmp   = fp;  fp += (size_t)PP * DD;
  float* Opart = fp;  fp += (size_t)NS * PP * DD;
  float* stats = fp;  fp += (size_t)NS * PP * HN * 2;
  short* sp = (short*)fp;
  short* x_bf    = sp;  sp += (size_t)PP * DD;
  short* enc_bf  = sp;  sp += (size_t)PP * DD;
  short* qkv_bf  = sp;  sp += (size_t)PP * 3 * DD;
  short* attno_bf= sp;  sp += (size_t)PP * DD;
  short* ffh_bf  = sp;  sp += (size_t)PP * DFF_;
  short* wslot0  = sp;  sp += (size_t)4 * 1024 * 1024;
  short* wslot1  = sp;  sp += (size_t)4 * 1024 * 1024;
  short* outw_bf = sp;  sp += (size_t)VV * DD;

  const dim3 b256(256);
  const dim3 gFA(PP / 64, HN, NS);
  const dim3 gQKV(3 * DD / 128, PP / 128);
  const dim3 gFF1(DFF_ / 128, PP / 128);
  const dim3 gDD64(DD / 64, PP / 64);
  const dim3 gKV64(2 * DD / 64, PP / 64);
  const dim3 gOUT(VV / 64, PP / 64);

  auto cvt_launch = [&](CvtSeg* segs, int cnt) {
    CvtArgs a;
    int mx = 0;
    for (int i = 0; i < 6; ++i) {
      if (i < cnt) { a.seg[i] = segs[i]; if (segs[i].n > mx) mx = segs[i].n; }
      else { a.seg[i].src = nullptr; a.seg[i].dst = nullptr; a.seg[i].n = 0; }
    }
    dim3 g((mx + 2047) / 2048, 6);
    convert_bf16_kernel<<<g, b256, 0, stream>>>(a);
  };

  // per-layer weight slot offsets (shorts)
  // enc: inw@0 (786432), ow@786432 (262144), w1@1048576 (1048576), w2@2097152 (1048576)
  // dec: sawv@0 (262144), saow@262144, cainw@524288 (786432), caow@1310720 (262144),
  //      w1@1572864 (1048576), w2@2621440 (1048576)
  auto enc_cvt = [&](int l, short* slot) {
    CvtSeg s[4] = {
      {enc_inw + (size_t)l * 3 * DD * DD, slot,           3 * DD * DD},
      {enc_ow  + (size_t)l * DD * DD,     slot + 786432,  DD * DD},
      {enc_w1  + (size_t)l * DFF_ * DD,   slot + 1048576, DFF_ * DD},
      {enc_w2  + (size_t)l * DD * DFF_,   slot + 2097152, DD * DFF_}};
    cvt_launch(s, 4);
  };
  auto dec_cvt = [&](int l, short* slot) {
    CvtSeg s[6] = {
      {dec_sa_inw + (size_t)l * 3 * DD * DD + (size_t)2 * DD * DD, slot,           DD * DD},
      {dec_sa_ow  + (size_t)l * DD * DD,                           slot + 262144,  DD * DD},
      {dec_ca_inw + (size_t)l * 3 * DD * DD,                       slot + 524288,  3 * DD * DD},
      {dec_ca_ow  + (size_t)l * DD * DD,                           slot + 1310720, DD * DD},
      {dec_w1     + (size_t)l * DFF_ * DD,                         slot + 1572864, DFF_ * DD},
      {dec_w2     + (size_t)l * DD * DFF_,                         slot + 2621440, DD * DFF_}};
    cvt_launch(s, 6);
  };

  embed_mean_kernel<<<PP, b256, 0, stream>>>(bytes, emb, x, x_bf, tok);

  // out_w conversion (one-off)
  {
    CvtSeg s[1] = {{out_w, outw_bf, VV * DD}};
    cvt_launch(s, 1);
  }
  enc_cvt(0, wslot0);

  // ---------------- encoder ----------------
  for (int l = 0; l < LL; ++l) {
    short* slot = (l & 1) ? wslot1 : wslot0;
    if (l + 1 < LL) enc_cvt(l + 1, (l + 1) & 1 ? wslot1 : wslot0);
    const float* inb = enc_inb + (size_t)l * 3 * DD;
    const float* ob  = enc_ob  + (size_t)l * DD;
    const float* b1  = enc_b1  + (size_t)l * DFF_;
    const float* b2  = enc_b2  + (size_t)l * DD;

    gemm_mfma_kernel<128, 128, 0, 0, 1><<<gQKV, b256, 0, stream>>>(
        x_bf, DD, slot, DD, inb, nullptr, qkv_bf, 3 * DD, DD);
    flash_attn_mfma_kernel<<<gFA, b256, 0, stream>>>(qkv_bf, Opart, stats);
    attn_combine_kernel<<<PP, b256, 0, stream>>>(Opart, stats, attno_bf);
    gemm_mfma_kernel<64, 64, 0, 1, 0><<<gDD64, b256, 0, stream>>>(
        attno_bf, DD, slot + 786432, DD, ob, tmp, nullptr, DD, DD);
    ln_residual_kernel<<<PP / 4, b256, 0, stream>>>(
        x, tmp, enc_ln1w + (size_t)l * DD, enc_ln1b + (size_t)l * DD, x, x_bf);
    gemm_mfma_kernel<128, 128, 1, 0, 1><<<gFF1, b256, 0, stream>>>(
        x_bf, DD, slot + 1048576, DD, b1, nullptr, ffh_bf, DFF_, DD);
    gemm_mfma_kernel<64, 64, 0, 1, 0><<<gDD64, b256, 0, stream>>>(
        ffh_bf, DFF_, slot + 2097152, DFF_, b2, tmp, nullptr, DD, DFF_);
    ln_residual_kernel<<<PP / 4, b256, 0, stream>>>(
        x, tmp, enc_ln2w + (size_t)l * DD, enc_ln2b + (size_t)l * DD, x, x_bf);
  }

  copy_dual_kernel<<<(PP * DD / 8) / 256, b256, 0, stream>>>(enc, enc_bf, x);
  gate_mix_kernel<<<PP / 4, b256, 0, stream>>>(enc, tok, alpha, x, x_bf);

  dec_cvt(0, wslot0);

  // ---------------- decoder ----------------
  for (int l = 0; l < LL; ++l) {
    short* slot = (l & 1) ? wslot1 : wslot0;
    if (l + 1 < LL) dec_cvt(l + 1, (l + 1) & 1 ? wslot1 : wslot0);
    const float* sa_bv = dec_sa_inb + (size_t)l * 3 * DD + 2 * DD;
    const float* sa_ob = dec_sa_ob + (size_t)l * DD;
    const float* ca_inb = dec_ca_inb + (size_t)l * 3 * DD;
    const float* ca_ob  = dec_ca_ob + (size_t)l * DD;
    const float* b1 = dec_b1 + (size_t)l * DFF_;
    const float* b2 = dec_b2 + (size_t)l * DD;

    // self path (value-only)
    gemm_mfma_kernel<64, 64, 0, 0, 1><<<gDD64, b256, 0, stream>>>(
        x_bf, DD, slot, DD, sa_bv, nullptr, attno_bf, DD, DD);
    gemm_mfma_kernel<64, 64, 0, 1, 0><<<gDD64, b256, 0, stream>>>(
        attno_bf, DD, slot + 262144, DD, sa_ob, tmp, nullptr, DD, DD);
    ln_residual_kernel<<<PP / 4, b256, 0, stream>>>(
        x, tmp, dec_ln1w + (size_t)l * DD, dec_ln1b + (size_t)l * DD, x, x_bf);

    // cross-attention
    gemm_mfma_kernel<64, 64, 0, 0, 1><<<gDD64, b256, 0, stream>>>(
        x_bf, DD, slot + 524288, DD, ca_inb, nullptr, qkv_bf, 3 * DD, DD);
    gemm_mfma_kernel<64, 64, 0, 0, 1><<<gKV64, b256, 0, stream>>>(
        enc_bf, DD, slot + 524288 + DD * DD, DD, ca_inb + DD, nullptr, qkv_bf + DD, 3 * DD, DD);
    flash_attn_mfma_kernel<<<gFA, b256, 0, stream>>>(qkv_bf, Opart, stats);
    attn_combine_kernel<<<PP, b256, 0, stream>>>(Opart, stats, attno_bf);
    gemm_mfma_kernel<64, 64, 0, 1, 0><<<gDD64, b256, 0, stream>>>(
        attno_bf, DD, slot + 1310720, DD, ca_ob, tmp, nullptr, DD, DD);
    ln_residual_kernel<<<PP / 4, b256, 0, stream>>>(
        x, tmp, dec_ln2w + (size_t)l * DD, dec_ln2b + (size_t)l * DD, x, x_bf);

    // FFN
    gemm_mfma_kernel<128, 128, 1, 0, 1><<<gFF1, b256, 0, stream>>>(
        x_bf, DD, slot + 1572864, DD, b1, nullptr, ffh_bf, DFF_, DD);
    gemm_mfma_kernel<64, 64, 0, 1, 0><<<gDD64, b256, 0, stream>>>(
        ffh_bf, DFF_, slot + 2621440, DFF_, b2, tmp, nullptr, DD, DFF_);
    ln_residual_kernel<<<PP / 4, b256, 0, stream>>>(
        x, tmp, dec_ln3w + (size_t)l * DD, dec_ln3b + (size_t)l * DD, x, x_bf);
  }

  gemm_mfma_kernel<64, 64, 0, 1, 0><<<gOUT, b256, 0, stream>>>(
      x_bf, DD, outw_bf, DD, out_b, (float*)d_out, nullptr, VV, DD);
}

// Round 4
// 1639.008 us; speedup vs baseline: 3.5154x; 1.0109x over previous
//
#include <hip/hip_runtime.h>
#include <hip/hip_bf16.h>
#include <math.h>

#define DD   512
#define HN   8
#define DHD  64
#define LL   6
#define DFF_ 2048
#define VV   256
#define KB_  5
#define PP   2048
#define EPS_ 1e-5f
#define TAU_ 0.1f
#define NS   4          // KV splits for flash attention
#define KVS  (PP / NS)  // 512 keys per split

typedef __attribute__((ext_vector_type(8))) short bf16x8;
typedef __attribute__((ext_vector_type(4))) short bf16x4;
typedef __attribute__((ext_vector_type(4))) float f32x4;

// ---------------- helpers ----------------
__device__ __forceinline__ float wave_sum(float v) {
#pragma unroll
  for (int m = 32; m >= 1; m >>= 1) v += __shfl_xor(v, m, 64);
  return v;
}

__device__ __forceinline__ unsigned short f2bf(float f) {
  unsigned u = __float_as_uint(f);
  u += 0x7FFF + ((u >> 16) & 1);   // RNE
  return (unsigned short)(u >> 16);
}

__device__ __forceinline__ bf16x8 cvt8(float4 a, float4 b) {
  bf16x8 v;
  v[0] = (short)f2bf(a.x); v[1] = (short)f2bf(a.y);
  v[2] = (short)f2bf(a.z); v[3] = (short)f2bf(a.w);
  v[4] = (short)f2bf(b.x); v[5] = (short)f2bf(b.y);
  v[6] = (short)f2bf(b.z); v[7] = (short)f2bf(b.w);
  return v;
}

// ---------------- batched fp32 -> bf16 convert ----------------
struct CvtSeg { const float* src; short* dst; int n; };
struct CvtArgs { CvtSeg seg[6]; };

__global__ __launch_bounds__(256) void convert_bf16_kernel(CvtArgs a) {
  const CvtSeg sg = a.seg[blockIdx.y];
  const int i = ((int)blockIdx.x * 256 + (int)threadIdx.x) * 8;
  if (i >= sg.n) return;
  const float4 x0 = *(const float4*)(sg.src + i);
  const float4 x1 = *(const float4*)(sg.src + i + 4);
  *(bf16x8*)(sg.dst + i) = cvt8(x0, x1);
}

// ---------------- embedding ----------------
__global__ __launch_bounds__(256) void embed_mean_kernel(const int* __restrict__ bytes,
                                                         const float* __restrict__ emb,
                                                         float* __restrict__ x,
                                                         short* __restrict__ xb,
                                                         float* __restrict__ tok) {
  const int p = blockIdx.x;
  const int d = threadIdx.x * 2;
  float a0 = 0.f, a1 = 0.f;
  int last = 0;
#pragma unroll
  for (int k = 0; k < KB_; ++k) {
    const int idx = bytes[p * KB_ + k];
    last = idx;
    const float* e = emb + (size_t)idx * DD + d;
    a0 += e[0]; a1 += e[1];
  }
  a0 *= 0.2f; a1 *= 0.2f;
  x[(size_t)p * DD + d]     = a0;
  x[(size_t)p * DD + d + 1] = a1;
  xb[(size_t)p * DD + d]     = (short)f2bf(a0);
  xb[(size_t)p * DD + d + 1] = (short)f2bf(a1);
  const float* e = emb + (size_t)last * DD + d;
  tok[(size_t)p * DD + d]     = e[0];
  tok[(size_t)p * DD + d + 1] = e[1];
}

// ---------------- MFMA GEMM (bf16 in, fp32 accum): C = A @ W^T + bias ----------------
// A[M x Kd] bf16, W[N x Kd] bf16, both K-contiguous. BM in {64,128}, BN in {32,64,128}.
template <int BM, int BN, int RELU, int WF32, int WBF16>
__global__ __launch_bounds__(256) void gemm_mfma_kernel(
    const short* __restrict__ A, int lda,
    const short* __restrict__ W, int ldw,
    const float* __restrict__ bias,
    float* __restrict__ Cf, short* __restrict__ Cb, int ldc, int Kd) {
  __shared__ short As[BM * 32];
  __shared__ short Bs[BN * 32];
  constexpr int WM = BM / 2, WN = BN / 2;
  constexpr int MF = WM / 16, NF = WN / 16;
  const int tid = (int)threadIdx.x;
  const int lane = tid & 63;
  const int wid = tid >> 6;
  const int wm = (wid >> 1) * WM;
  const int wn = (wid & 1) * WN;
  const int bm = blockIdx.y * BM;
  const int bn = blockIdx.x * BN;
  const int sr = tid >> 2;          // staging row 0..63
  const int sc = (tid & 3) * 8;     // staging col 0,8,16,24
  const int fr = lane & 15;
  const int kg = (lane >> 4) * 8;

  f32x4 acc[MF][NF];
#pragma unroll
  for (int i = 0; i < MF; ++i)
#pragma unroll
    for (int j = 0; j < NF; ++j) acc[i][j] = (f32x4){0.f, 0.f, 0.f, 0.f};

  for (int k0 = 0; k0 < Kd; k0 += 32) {
    __syncthreads();
#pragma unroll
    for (int p = 0; p < BM; p += 64)
      *(bf16x8*)&As[(p + sr) * 32 + sc] =
          *(const bf16x8*)&A[(size_t)(bm + p + sr) * lda + k0 + sc];
    if constexpr (BN >= 64) {
#pragma unroll
      for (int p = 0; p < BN; p += 64)
        *(bf16x8*)&Bs[(p + sr) * 32 + sc] =
            *(const bf16x8*)&W[(size_t)(bn + p + sr) * ldw + k0 + sc];
    } else {
      if (sr < BN)
        *(bf16x8*)&Bs[sr * 32 + sc] =
            *(const bf16x8*)&W[(size_t)(bn + sr) * ldw + k0 + sc];
    }
    __syncthreads();
    bf16x8 af[MF], bfr[NF];
#pragma unroll
    for (int i = 0; i < MF; ++i)
      af[i] = *(const bf16x8*)&As[(wm + i * 16 + fr) * 32 + kg];
#pragma unroll
    for (int j = 0; j < NF; ++j)
      bfr[j] = *(const bf16x8*)&Bs[(wn + j * 16 + fr) * 32 + kg];
#pragma unroll
    for (int i = 0; i < MF; ++i)
#pragma unroll
      for (int j = 0; j < NF; ++j)
        acc[i][j] = __builtin_amdgcn_mfma_f32_16x16x32_bf16(af[i], bfr[j], acc[i][j], 0, 0, 0);
  }

  const int cr = (lane >> 4) * 4;
#pragma unroll
  for (int j = 0; j < NF; ++j) {
    const int col = bn + wn + j * 16 + fr;
    const float bb = bias[col];
#pragma unroll
    for (int i = 0; i < MF; ++i) {
#pragma unroll
      for (int r = 0; r < 4; ++r) {
        float v = acc[i][j][r] + bb;
        if (RELU) v = fmaxf(v, 0.f);
        const size_t idx = (size_t)(bm + wm + i * 16 + cr + r) * ldc + col;
        if (WF32) Cf[idx] = v;
        if (WBF16) Cb[idx] = (short)f2bf(v);
      }
    }
  }
}

// ---------------- MFMA flash attention (swapped QK^T), KV split ----------------
// qkvb: P x 3D bf16. Opart: [NS][P][D] fp32 raw. stats: [NS][P][H] float2 (m,l).
__global__ __launch_bounds__(256) void flash_attn_mfma_kernel(const short* __restrict__ qkvb,
                                                              float* __restrict__ Opart,
                                                              float* __restrict__ stats) {
  constexpr int LS = 72;
  __shared__ short Ks[64 * LS];
  __shared__ short Vt[64 * LS];  // transposed: row = d, col = key
  __shared__ short Ps[64 * LS];  // row = query(0..63), col = key
  const int h = blockIdx.y;
  const int q0 = blockIdx.x * 64;
  const int sp = blockIdx.z;
  const int tid = (int)threadIdx.x;
  const int lane = tid & 63;
  const int wid = tid >> 6;
  const int fr = lane & 15;
  const int g = lane >> 4;
  const int kg = g * 8;

  // Q fragment (identical register layout for A- or B-operand use):
  // lane&15 -> query within wave band, k(d) = kg + j
  bf16x8 qf[2];
  {
    const short* src = qkvb + (size_t)(q0 + wid * 16 + fr) * (3 * DD) + h * DHD + kg;
    qf[0] = *(const bf16x8*)src;
    qf[1] = *(const bf16x8*)(src + 32);
  }

  f32x4 acc_o[4];
#pragma unroll
  for (int df = 0; df < 4; ++df) acc_o[df] = (f32x4){0.f, 0.f, 0.f, 0.f};
  float mreg = -INFINITY, lsum = 0.f;   // per-lane: stats of query fr

  const int sr8 = tid >> 3;          // 0..31
  const int sc8 = (tid & 7) * 8;     // 0..56
  const int vk = tid & 63;           // key
  const int vd = (tid >> 6) * 8;     // d0: 0,8,16,24

  for (int t = 0; t < KVS / 64; ++t) {
    const int k0 = sp * KVS + t * 64;
    __syncthreads();
    {
#pragma unroll
      for (int p = 0; p < 64; p += 32)
        *(bf16x8*)&Ks[(sr8 + p) * LS + sc8] =
            *(const bf16x8*)&qkvb[(size_t)(k0 + sr8 + p) * (3 * DD) + DD + h * DHD + sc8];
#pragma unroll
      for (int p = 0; p < 64; p += 32) {
        const bf16x8 v = *(const bf16x8*)&qkvb[(size_t)(k0 + vk) * (3 * DD) + 2 * DD + h * DHD + vd + p];
#pragma unroll
        for (int j = 0; j < 8; ++j) Vt[(vd + p + j) * LS + vk] = v[j];
      }
    }
    __syncthreads();

    // S^T = K @ Q^T : col = lane&15 = query, row(reg) = key nf*16 + g*4 + i
    f32x4 st[4];
#pragma unroll
    for (int nf = 0; nf < 4; ++nf) st[nf] = (f32x4){0.f, 0.f, 0.f, 0.f};
#pragma unroll
    for (int nf = 0; nf < 4; ++nf) {
      const bf16x8 kf0 = *(const bf16x8*)&Ks[(nf * 16 + fr) * LS + kg];
      const bf16x8 kf1 = *(const bf16x8*)&Ks[(nf * 16 + fr) * LS + kg + 32];
      st[nf] = __builtin_amdgcn_mfma_f32_16x16x32_bf16(kf0, qf[0], st[nf], 0, 0, 0);
      st[nf] = __builtin_amdgcn_mfma_f32_16x16x32_bf16(kf1, qf[1], st[nf], 0, 0, 0);
    }

    // online softmax, fully lane-local for query fr (16 key-scores in regs)
    float mx = st[0][0];
#pragma unroll
    for (int nf = 0; nf < 4; ++nf)
#pragma unroll
      for (int i = 0; i < 4; ++i) mx = fmaxf(mx, st[nf][i]);
    mx *= 0.125f;
    mx = fmaxf(mx, __shfl_xor(mx, 16, 64));
    mx = fmaxf(mx, __shfl_xor(mx, 32, 64));
    const float mn = fmaxf(mreg, mx);
    const float corr = __expf(mreg - mn);
    mreg = mn;
    float pv[4][4];
    float sum = 0.f;
#pragma unroll
    for (int nf = 0; nf < 4; ++nf)
#pragma unroll
      for (int i = 0; i < 4; ++i) {
        pv[nf][i] = __expf(fmaf(st[nf][i], 0.125f, -mn));
        sum += pv[nf][i];
      }
    sum += __shfl_xor(sum, 16, 64);
    sum += __shfl_xor(sum, 32, 64);
    lsum = lsum * corr + sum;

    // redistribute corr into PV accumulator layout (row = query g*4+i)
    float corr_acc[4];
#pragma unroll
    for (int i = 0; i < 4; ++i)
      corr_acc[i] = __shfl(corr, (lane & 48) | (g * 4 + i), 64);
#pragma unroll
    for (int df = 0; df < 4; ++df) {
      acc_o[df][0] *= corr_acc[0]; acc_o[df][1] *= corr_acc[1];
      acc_o[df][2] *= corr_acc[2]; acc_o[df][3] *= corr_acc[3];
    }

    // P -> LDS bf16: row = wave-band query fr, cols keys nf*16+g*4+{0..3} (b64 packed)
#pragma unroll
    for (int nf = 0; nf < 4; ++nf) {
      bf16x4 pw;
#pragma unroll
      for (int i = 0; i < 4; ++i) pw[i] = (short)f2bf(pv[nf][i]);
      *(bf16x4*)&Ps[(wid * 16 + fr) * LS + nf * 16 + g * 4] = pw;
    }
    asm volatile("s_waitcnt lgkmcnt(0)" ::: "memory");

    // PV: A = P (m=query, k=key), B = Vt (k=key, n=d)
    const bf16x8 pa0 = *(const bf16x8*)&Ps[(wid * 16 + fr) * LS + kg];
    const bf16x8 pa1 = *(const bf16x8*)&Ps[(wid * 16 + fr) * LS + kg + 32];
#pragma unroll
    for (int df = 0; df < 4; ++df) {
      const bf16x8 vb0 = *(const bf16x8*)&Vt[(df * 16 + fr) * LS + kg];
      const bf16x8 vb1 = *(const bf16x8*)&Vt[(df * 16 + fr) * LS + kg + 32];
      acc_o[df] = __builtin_amdgcn_mfma_f32_16x16x32_bf16(pa0, vb0, acc_o[df], 0, 0, 0);
      acc_o[df] = __builtin_amdgcn_mfma_f32_16x16x32_bf16(pa1, vb1, acc_o[df], 0, 0, 0);
    }
  }

  // raw partial output + stats
  const int orow = q0 + wid * 16 + g * 4;
#pragma unroll
  for (int df = 0; df < 4; ++df)
#pragma unroll
    for (int i = 0; i < 4; ++i)
      Opart[((size_t)sp * PP + orow + i) * DD + h * DHD + df * 16 + fr] = acc_o[df][i];
  if (g == 0) {
    const size_t si = (((size_t)sp * PP + q0 + wid * 16 + fr) * HN + h) * 2;
    stats[si]     = mreg;
    stats[si + 1] = lsum;
  }
}

// ---------------- combine NS partials -> attno bf16 ----------------
__global__ __launch_bounds__(256) void attn_combine_kernel(const float* __restrict__ Opart,
                                                           const float* __restrict__ stats,
                                                           short* __restrict__ outb) {
  const int row = blockIdx.x;
  const int d = (int)threadIdx.x * 2;
  const int h = d >> 6;
  float m[NS], l[NS];
  float M = -INFINITY;
#pragma unroll
  for (int s = 0; s < NS; ++s) {
    const size_t si = (((size_t)s * PP + row) * HN + h) * 2;
    m[s] = stats[si]; l[s] = stats[si + 1];
    M = fmaxf(M, m[s]);
  }
  float L = 0.f, o0 = 0.f, o1 = 0.f;
#pragma unroll
  for (int s = 0; s < NS; ++s) {
    const float e = __expf(m[s] - M);
    L += l[s] * e;
    const float* op = Opart + ((size_t)s * PP + row) * DD + d;
    o0 += op[0] * e;
    o1 += op[1] * e;
  }
  const float inv = 1.f / L;
  outb[(size_t)row * DD + d]     = (short)f2bf(o0 * inv);
  outb[(size_t)row * DD + d + 1] = (short)f2bf(o1 * inv);
}

// ---------------- LN(x + res) * w + b -> out fp32 + bf16 ----------------
__global__ __launch_bounds__(256) void ln_residual_kernel(const float* __restrict__ xin,
                                                          const float* __restrict__ res,
                                                          const float* __restrict__ w,
                                                          const float* __restrict__ b,
                                                          float* __restrict__ out,
                                                          short* __restrict__ outb) {
  const int row = blockIdx.x * 4 + (threadIdx.x >> 6);
  const int lane = threadIdx.x & 63;
  const float* xr = xin + (size_t)row * DD + lane * 8;
  const float* rr = res + (size_t)row * DD + lane * 8;
  float v[8];
  {
    const float4 a0 = *(const float4*)xr;
    const float4 a1 = *(const float4*)(xr + 4);
    const float4 r0 = *(const float4*)rr;
    const float4 r1 = *(const float4*)(rr + 4);
    v[0] = a0.x + r0.x; v[1] = a0.y + r0.y; v[2] = a0.z + r0.z; v[3] = a0.w + r0.w;
    v[4] = a1.x + r1.x; v[5] = a1.y + r1.y; v[6] = a1.z + r1.z; v[7] = a1.w + r1.w;
  }
  float sum = 0.f;
#pragma unroll
  for (int j = 0; j < 8; ++j) sum += v[j];
  sum = wave_sum(sum);
  const float mean = sum * (1.f / DD);
  float sq = 0.f;
#pragma unroll
  for (int j = 0; j < 8; ++j) { const float dd = v[j] - mean; sq += dd * dd; }
  sq = wave_sum(sq);
  const float rstd = rsqrtf(sq * (1.f / DD) + EPS_);
  const float* wp = w + lane * 8;
  const float* bp = b + lane * 8;
  float o[8];
#pragma unroll
  for (int j = 0; j < 8; ++j) o[j] = (v[j] - mean) * rstd * wp[j] + bp[j];
  float* op = out + (size_t)row * DD + lane * 8;
  *(float4*)op = *(float4*)&o[0];
  *(float4*)(op + 4) = *(float4*)&o[4];
  bf16x8 ob;
#pragma unroll
  for (int j = 0; j < 8; ++j) ob[j] = (short)f2bf(o[j]);
  *(bf16x8*)&outb[(size_t)row * DD + lane * 8] = ob;
}

// ---------------- gate + mix ----------------
__global__ __launch_bounds__(256) void gate_mix_kernel(const float* __restrict__ enc,
                                                       const float* __restrict__ tok,
                                                       const float* __restrict__ alpha_p,
                                                       float* __restrict__ x,
                                                       short* __restrict__ xb) {
  const int row = blockIdx.x * 4 + (threadIdx.x >> 6);
  const int lane = threadIdx.x & 63;
  const float* er = enc + (size_t)row * DD + lane * 8;
  const float* tr = tok + (size_t)row * DD + lane * 8;
  float e[8], t[8];
  {
    const float4 a0 = *(const float4*)er;
    const float4 a1 = *(const float4*)(er + 4);
    const float4 b0 = *(const float4*)tr;
    const float4 b1 = *(const float4*)(tr + 4);
    e[0] = a0.x; e[1] = a0.y; e[2] = a0.z; e[3] = a0.w;
    e[4] = a1.x; e[5] = a1.y; e[6] = a1.z; e[7] = a1.w;
    t[0] = b0.x; t[1] = b0.y; t[2] = b0.z; t[3] = b0.w;
    t[4] = b1.x; t[5] = b1.y; t[6] = b1.z; t[7] = b1.w;
  }
  float sq = 0.f;
#pragma unroll
  for (int j = 0; j < 8; ++j) sq += e[j] * e[j];
  sq = wave_sum(sq);
  const bool gate = sq > TAU_ * TAU_;
  const float a = *alpha_p;
  float o[8];
#pragma unroll
  for (int j = 0; j < 8; ++j) o[j] = gate ? (a * e[j] + (1.f - a) * t[j]) : t[j];
  float* op = x + (size_t)row * DD + lane * 8;
  *(float4*)op = *(float4*)&o[0];
  *(float4*)(op + 4) = *(float4*)&o[4];
  bf16x8 ob;
#pragma unroll
  for (int j = 0; j < 8; ++j) ob[j] = (short)f2bf(o[j]);
  *(bf16x8*)&xb[(size_t)row * DD + lane * 8] = ob;
}

// ---------------- copy x -> enc (fp32 + bf16) ----------------
__global__ __launch_bounds__(256) void copy_dual_kernel(float* __restrict__ dst,
                                                        short* __restrict__ dstb,
                                                        const float* __restrict__ src) {
  const size_t i = ((size_t)blockIdx.x * 256 + threadIdx.x) * 8;
  const float4 a0 = *(const float4*)&src[i];
  const float4 a1 = *(const float4*)&src[i + 4];
  *(float4*)&dst[i] = a0;
  *(float4*)&dst[i + 4] = a1;
  *(bf16x8*)&dstb[i] = cvt8(a0, a1);
}

// ---------------- launch ----------------
extern "C" void kernel_launch(void* const* d_in, const int* in_sizes, int n_in,
                              void* d_out, int out_size, void* d_ws, size_t ws_size,
                              hipStream_t stream) {
  const int*   bytes    = (const int*)d_in[0];
  const float* emb      = (const float*)d_in[1];
  const float* alpha    = (const float*)d_in[2];
  const float* enc_inw  = (const float*)d_in[3];
  const float* enc_inb  = (const float*)d_in[4];
  const float* enc_ow   = (const float*)d_in[5];
  const float* enc_ob   = (const float*)d_in[6];
  const float* enc_w1   = (const float*)d_in[7];
  const float* enc_b1   = (const float*)d_in[8];
  const float* enc_w2   = (const float*)d_in[9];
  const float* enc_b2   = (const float*)d_in[10];
  const float* enc_ln1w = (const float*)d_in[11];
  const float* enc_ln1b = (const float*)d_in[12];
  const float* enc_ln2w = (const float*)d_in[13];
  const float* enc_ln2b = (const float*)d_in[14];
  const float* dec_sa_inw = (const float*)d_in[15];
  const float* dec_sa_inb = (const float*)d_in[16];
  const float* dec_sa_ow  = (const float*)d_in[17];
  const float* dec_sa_ob  = (const float*)d_in[18];
  const float* dec_ca_inw = (const float*)d_in[19];
  const float* dec_ca_inb = (const float*)d_in[20];
  const float* dec_ca_ow  = (const float*)d_in[21];
  const float* dec_ca_ob  = (const float*)d_in[22];
  const float* dec_w1   = (const float*)d_in[23];
  const float* dec_b1   = (const float*)d_in[24];
  const float* dec_w2   = (const float*)d_in[25];
  const float* dec_b2   = (const float*)d_in[26];
  const float* dec_ln1w = (const float*)d_in[27];
  const float* dec_ln1b = (const float*)d_in[28];
  const float* dec_ln2w = (const float*)d_in[29];
  const float* dec_ln2b = (const float*)d_in[30];
  const float* dec_ln3w = (const float*)d_in[31];
  const float* dec_ln3b = (const float*)d_in[32];
  const float* out_w    = (const float*)d_in[33];
  const float* out_b    = (const float*)d_in[34];

  // ---- workspace layout ----
  float* fp = (float*)d_ws;
  float* x     = fp;  fp += (size_t)PP * DD;
  float* enc   = fp;  fp += (size_t)PP * DD;
  float* tok   = fp;  fp += (size_t)PP * DD;
  float* tmp   = fp;  fp += (size_t)PP * DD;
  float* Opart = fp;  fp += (size_t)NS * PP * DD;
  float* stats = fp;  fp += (size_t)NS * PP * HN * 2;
  short* sp = (short*)fp;
  short* x_bf    = sp;  sp += (size_t)PP * DD;
  short* enc_bf  = sp;  sp += (size_t)PP * DD;
  short* qkv_bf  = sp;  sp += (size_t)PP * 3 * DD;
  short* attno_bf= sp;  sp += (size_t)PP * DD;
  short* ffh_bf  = sp;  sp += (size_t)PP * DFF_;
  short* wslot0  = sp;  sp += (size_t)4 * 1024 * 1024;
  short* wslot1  = sp;  sp += (size_t)4 * 1024 * 1024;
  short* outw_bf = sp;  sp += (size_t)VV * DD;

  const dim3 b256(256);
  const dim3 gFA(PP / 64, HN, NS);
  const dim3 gQKV(3 * DD / 64, PP / 128);      // <128,64>: 24 x 16 = 384
  const dim3 gFF1(DFF_ / 64, PP / 128);        // <128,64>: 32 x 16 = 512
  const dim3 gDD(DD / 32, PP / 64);            // <64,32>: 16 x 32 = 512
  const dim3 gKV(2 * DD / 32, PP / 64);        // <64,32>: 32 x 32 = 1024
  const dim3 gOUT(VV / 32, PP / 64);           // <64,32>: 8 x 32 = 256

  auto cvt_launch = [&](CvtSeg* segs, int cnt) {
    CvtArgs a;
    int mx = 0;
    for (int i = 0; i < 6; ++i) {
      if (i < cnt) { a.seg[i] = segs[i]; if (segs[i].n > mx) mx = segs[i].n; }
      else { a.seg[i].src = nullptr; a.seg[i].dst = nullptr; a.seg[i].n = 0; }
    }
    dim3 g((mx + 2047) / 2048, 6);
    convert_bf16_kernel<<<g, b256, 0, stream>>>(a);
  };

  auto enc_cvt = [&](int l, short* slot) {
    CvtSeg s[4] = {
      {enc_inw + (size_t)l * 3 * DD * DD, slot,           3 * DD * DD},
      {enc_ow  + (size_t)l * DD * DD,     slot + 786432,  DD * DD},
      {enc_w1  + (size_t)l * DFF_ * DD,   slot + 1048576, DFF_ * DD},
      {enc_w2  + (size_t)l * DD * DFF_,   slot + 2097152, DD * DFF_}};
    cvt_launch(s, 4);
  };
  auto dec_cvt = [&](int l, short* slot) {
    CvtSeg s[6] = {
      {dec_sa_inw + (size_t)l * 3 * DD * DD + (size_t)2 * DD * DD, slot,           DD * DD},
      {dec_sa_ow  + (size_t)l * DD * DD,                           slot + 262144,  DD * DD},
      {dec_ca_inw + (size_t)l * 3 * DD * DD,                       slot + 524288,  3 * DD * DD},
      {dec_ca_ow  + (size_t)l * DD * DD,                           slot + 1310720, DD * DD},
      {dec_w1     + (size_t)l * DFF_ * DD,                         slot + 1572864, DFF_ * DD},
      {dec_w2     + (size_t)l * DD * DFF_,                         slot + 2621440, DD * DFF_}};
    cvt_launch(s, 6);
  };

  embed_mean_kernel<<<PP, b256, 0, stream>>>(bytes, emb, x, x_bf, tok);

  {
    CvtSeg s[1] = {{out_w, outw_bf, VV * DD}};
    cvt_launch(s, 1);
  }
  enc_cvt(0, wslot0);

  // ---------------- encoder ----------------
  for (int l = 0; l < LL; ++l) {
    short* slot = (l & 1) ? wslot1 : wslot0;
    if (l + 1 < LL) enc_cvt(l + 1, (l + 1) & 1 ? wslot1 : wslot0);
    const float* inb = enc_inb + (size_t)l * 3 * DD;
    const float* ob  = enc_ob  + (size_t)l * DD;
    const float* b1  = enc_b1  + (size_t)l * DFF_;
    const float* b2  = enc_b2  + (size_t)l * DD;

    gemm_mfma_kernel<128, 64, 0, 0, 1><<<gQKV, b256, 0, stream>>>(
        x_bf, DD, slot, DD, inb, nullptr, qkv_bf, 3 * DD, DD);
    flash_attn_mfma_kernel<<<gFA, b256, 0, stream>>>(qkv_bf, Opart, stats);
    attn_combine_kernel<<<PP, b256, 0, stream>>>(Opart, stats, attno_bf);
    gemm_mfma_kernel<64, 32, 0, 1, 0><<<gDD, b256, 0, stream>>>(
        attno_bf, DD, slot + 786432, DD, ob, tmp, nullptr, DD, DD);
    ln_residual_kernel<<<PP / 4, b256, 0, stream>>>(
        x, tmp, enc_ln1w + (size_t)l * DD, enc_ln1b + (size_t)l * DD, x, x_bf);
    gemm_mfma_kernel<128, 64, 1, 0, 1><<<gFF1, b256, 0, stream>>>(
        x_bf, DD, slot + 1048576, DD, b1, nullptr, ffh_bf, DFF_, DD);
    gemm_mfma_kernel<64, 32, 0, 1, 0><<<gDD, b256, 0, stream>>>(
        ffh_bf, DFF_, slot + 2097152, DFF_, b2, tmp, nullptr, DD, DFF_);
    ln_residual_kernel<<<PP / 4, b256, 0, stream>>>(
        x, tmp, enc_ln2w + (size_t)l * DD, enc_ln2b + (size_t)l * DD, x, x_bf);
  }

  copy_dual_kernel<<<(PP * DD / 8) / 256, b256, 0, stream>>>(enc, enc_bf, x);
  gate_mix_kernel<<<PP / 4, b256, 0, stream>>>(enc, tok, alpha, x, x_bf);

  dec_cvt(0, wslot0);

  // ---------------- decoder ----------------
  for (int l = 0; l < LL; ++l) {
    short* slot = (l & 1) ? wslot1 : wslot0;
    if (l + 1 < LL) dec_cvt(l + 1, (l + 1) & 1 ? wslot1 : wslot0);
    const float* sa_bv = dec_sa_inb + (size_t)l * 3 * DD + 2 * DD;
    const float* sa_ob = dec_sa_ob + (size_t)l * DD;
    const float* ca_inb = dec_ca_inb + (size_t)l * 3 * DD;
    const float* ca_ob  = dec_ca_ob + (size_t)l * DD;
    const float* b1 = dec_b1 + (size_t)l * DFF_;
    const float* b2 = dec_b2 + (size_t)l * DD;

    // self path (value-only)
    gemm_mfma_kernel<64, 32, 0, 0, 1><<<gDD, b256, 0, stream>>>(
        x_bf, DD, slot, DD, sa_bv, nullptr, attno_bf, DD, DD);
    gemm_mfma_kernel<64, 32, 0, 1, 0><<<gDD, b256, 0, stream>>>(
        attno_bf, DD, slot + 262144, DD, sa_ob, tmp, nullptr, DD, DD);
    ln_residual_kernel<<<PP / 4, b256, 0, stream>>>(
        x, tmp, dec_ln1w + (size_t)l * DD, dec_ln1b + (size_t)l * DD, x, x_bf);

    // cross-attention
    gemm_mfma_kernel<64, 32, 0, 0, 1><<<gDD, b256, 0, stream>>>(
        x_bf, DD, slot + 524288, DD, ca_inb, nullptr, qkv_bf, 3 * DD, DD);
    gemm_mfma_kernel<64, 32, 0, 0, 1><<<gKV, b256, 0, stream>>>(
        enc_bf, DD, slot + 524288 + DD * DD, DD, ca_inb + DD, nullptr, qkv_bf + DD, 3 * DD, DD);
    flash_attn_mfma_kernel<<<gFA, b256, 0, stream>>>(qkv_bf, Opart, stats);
    attn_combine_kernel<<<PP, b256, 0, stream>>>(Opart, stats, attno_bf);
    gemm_mfma_kernel<64, 32, 0, 1, 0><<<gDD, b256, 0, stream>>>(
        attno_bf, DD, slot + 1310720, DD, ca_ob, tmp, nullptr, DD, DD);
    ln_residual_kernel<<<PP / 4, b256, 0, stream>>>(
        x, tmp, dec_ln2w + (size_t)l * DD, dec_ln2b + (size_t)l * DD, x, x_bf);

    // FFN
    gemm_mfma_kernel<128, 64, 1, 0, 1><<<gFF1, b256, 0, stream>>>(
        x_bf, DD, slot + 1572864, DD, b1, nullptr, ffh_bf, DFF_, DD);
    gemm_mfma_kernel<64, 32, 0, 1, 0><<<gDD, b256, 0, stream>>>(
        ffh_bf, DFF_, slot + 2621440, DFF_, b2, tmp, nullptr, DD, DFF_);
    ln_residual_kernel<<<PP / 4, b256, 0, stream>>>(
        x, tmp, dec_ln3w + (size_t)l * DD, dec_ln3b + (size_t)l * DD, x, x_bf);
  }

  gemm_mfma_kernel<64, 32, 0, 1, 0><<<gOUT, b256, 0, stream>>>(
      x_bf, DD, outw_bf, DD, out_b, (float*)d_out, nullptr, VV, DD);
}

// Round 5
// 1232.476 us; speedup vs baseline: 4.6749x; 1.3298x over previous
//
#include <hip/hip_runtime.h>
#include <hip/hip_bf16.h>
#include <math.h>

#define DD   512
#define HN   8
#define DHD  64
#define LL   6
#define DFF_ 2048
#define VV   256
#define KB_  5
#define PP   2048
#define EPS_ 1e-5f
#define TAU_ 0.1f
#define NS   4          // KV splits for flash attention
#define KVS  (PP / NS)  // 512 keys per split

typedef __attribute__((ext_vector_type(8))) short bf16x8;
typedef __attribute__((ext_vector_type(4))) short bf16x4;
typedef __attribute__((ext_vector_type(4))) float f32x4;

// ---------------- helpers ----------------
__device__ __forceinline__ float wave_sum(float v) {
#pragma unroll
  for (int m = 32; m >= 1; m >>= 1) v += __shfl_xor(v, m, 64);
  return v;
}

__device__ __forceinline__ unsigned short f2bf(float f) {
  unsigned u = __float_as_uint(f);
  u += 0x7FFF + ((u >> 16) & 1);   // RNE
  return (unsigned short)(u >> 16);
}

__device__ __forceinline__ bf16x8 cvt8(float4 a, float4 b) {
  bf16x8 v;
  v[0] = (short)f2bf(a.x); v[1] = (short)f2bf(a.y);
  v[2] = (short)f2bf(a.z); v[3] = (short)f2bf(a.w);
  v[4] = (short)f2bf(b.x); v[5] = (short)f2bf(b.y);
  v[6] = (short)f2bf(b.z); v[7] = (short)f2bf(b.w);
  return v;
}

__device__ __forceinline__ void gload16(const void* g, void* l) {
  __builtin_amdgcn_global_load_lds(
      (const __attribute__((address_space(1))) unsigned int*)g,
      (__attribute__((address_space(3))) unsigned int*)l, 16, 0, 0);
}

// ---------------- batched fp32 -> bf16 convert (all weights, one launch) ----------------
#define NSEG 61
struct CvtSeg { const float* src; short* dst; int n; };
struct CvtArgs { CvtSeg seg[NSEG]; };

__global__ __launch_bounds__(256) void convert_bf16_kernel(CvtArgs a) {
  const CvtSeg sg = a.seg[blockIdx.y];
  const int i = ((int)blockIdx.x * 256 + (int)threadIdx.x) * 8;
  if (i >= sg.n) return;
  const float4 x0 = *(const float4*)(sg.src + i);
  const float4 x1 = *(const float4*)(sg.src + i + 4);
  *(bf16x8*)(sg.dst + i) = cvt8(x0, x1);
}

// ---------------- embedding ----------------
__global__ __launch_bounds__(256) void embed_mean_kernel(const int* __restrict__ bytes,
                                                         const float* __restrict__ emb,
                                                         float* __restrict__ x,
                                                         short* __restrict__ xb,
                                                         float* __restrict__ tok) {
  const int p = blockIdx.x;
  const int d = threadIdx.x * 2;
  float a0 = 0.f, a1 = 0.f;
  int last = 0;
#pragma unroll
  for (int k = 0; k < KB_; ++k) {
    const int idx = bytes[p * KB_ + k];
    last = idx;
    const float* e = emb + (size_t)idx * DD + d;
    a0 += e[0]; a1 += e[1];
  }
  a0 *= 0.2f; a1 *= 0.2f;
  x[(size_t)p * DD + d]     = a0;
  x[(size_t)p * DD + d + 1] = a1;
  xb[(size_t)p * DD + d]     = (short)f2bf(a0);
  xb[(size_t)p * DD + d + 1] = (short)f2bf(a1);
  const float* e = emb + (size_t)last * DD + d;
  tok[(size_t)p * DD + d]     = e[0];
  tok[(size_t)p * DD + d + 1] = e[1];
}

// ---------------- MFMA GEMM with global_load_lds + XOR-swizzled LDS ----------------
// C[M x N] = A[M x Kd] @ W[N x Kd]^T (+ bias). A, W bf16 K-contiguous.
// BK=64. LDS tile [rows][64] bf16 (128 B/row), swizzle: LDS(r,cg) = global(r, cg^(r&7)),
// cg = 16-byte column group. gload_lds writes linear; source address pre-swizzled.
// NSPLIT>1: blockIdx.z selects K-half, writes raw fp32 partial at Cf + z*pstride.
template <int BM, int BN, int NSPLIT, int RELU, int WF32, int WBF16>
__global__ __launch_bounds__(256) void gemm_gl_kernel(
    const short* __restrict__ A, int lda,
    const short* __restrict__ W, int ldw,
    const float* __restrict__ bias,
    float* __restrict__ Cf, short* __restrict__ Cb, int ldc, int Kd,
    size_t pstride) {
  constexpr int BK = 64;
  __shared__ short As[BM * BK];
  __shared__ short Bs[BN * BK];
  constexpr int WM = BM / 2, WN = BN / 2;
  constexpr int MF = WM / 16, NF = WN / 16;
  const int tid = (int)threadIdx.x;
  const int lane = tid & 63;
  const int wid = tid >> 6;
  const int wm = (wid >> 1) * WM;
  const int wn = (wid & 1) * WN;
  const int bm = blockIdx.y * BM;
  const int bn = blockIdx.x * BN;
  const int fr = lane & 15;
  const int kq = lane >> 4;            // 0..3
  const int rs = fr & 7;               // read-side swizzle key (row&7)
  // staging: each wave-issue covers 8 rows x 128 B; lane -> (row=lane>>3, cg=lane&7)
  const int srow = lane >> 3;
  const int scg = (lane & 7) ^ srow;   // pre-swizzled source column-group

  const int kz = (NSPLIT > 1) ? (int)blockIdx.z : 0;
  const int kbeg = kz * (Kd / NSPLIT);
  const int kend = kbeg + Kd / NSPLIT;

  f32x4 acc[MF][NF];
#pragma unroll
  for (int i = 0; i < MF; ++i)
#pragma unroll
    for (int j = 0; j < NF; ++j) acc[i][j] = (f32x4){0.f, 0.f, 0.f, 0.f};

  for (int k0 = kbeg; k0 < kend; k0 += BK) {
    __syncthreads();
#pragma unroll
    for (int is = 0; is < BM / 32; ++is) {
      const int ib = is * 4 + wid;
      gload16(&A[(size_t)(bm + ib * 8 + srow) * lda + k0 + scg * 8], &As[ib * 512]);
    }
#pragma unroll
    for (int is = 0; is < BN / 32; ++is) {
      const int ib = is * 4 + wid;
      gload16(&W[(size_t)(bn + ib * 8 + srow) * ldw + k0 + scg * 8], &Bs[ib * 512]);
    }
    __syncthreads();   // compiler drains vmcnt before barrier
#pragma unroll
    for (int s = 0; s < 2; ++s) {
      const int cg = s * 4 + kq;       // unswizzled 16B col-group 0..7
      const int co = (cg ^ rs) * 8;    // swizzled short offset within row
      bf16x8 af[MF], bf[NF];
#pragma unroll
      for (int i = 0; i < MF; ++i)
        af[i] = *(const bf16x8*)&As[(wm + i * 16 + fr) * BK + co];
#pragma unroll
      for (int j = 0; j < NF; ++j)
        bf[j] = *(const bf16x8*)&Bs[(wn + j * 16 + fr) * BK + co];
#pragma unroll
      for (int i = 0; i < MF; ++i)
#pragma unroll
        for (int j = 0; j < NF; ++j)
          acc[i][j] = __builtin_amdgcn_mfma_f32_16x16x32_bf16(af[i], bf[j], acc[i][j], 0, 0, 0);
    }
  }

  const int cr = (lane >> 4) * 4;
  if constexpr (NSPLIT > 1) {
    float* dst = Cf + (size_t)kz * pstride;
#pragma unroll
    for (int j = 0; j < NF; ++j) {
      const int col = bn + wn + j * 16 + fr;
#pragma unroll
      for (int i = 0; i < MF; ++i)
#pragma unroll
        for (int r = 0; r < 4; ++r)
          dst[(size_t)(bm + wm + i * 16 + cr + r) * ldc + col] = acc[i][j][r];
    }
  } else {
#pragma unroll
    for (int j = 0; j < NF; ++j) {
      const int col = bn + wn + j * 16 + fr;
      const float bb = bias[col];
#pragma unroll
      for (int i = 0; i < MF; ++i) {
#pragma unroll
        for (int r = 0; r < 4; ++r) {
          float v = acc[i][j][r] + bb;
          if (RELU) v = fmaxf(v, 0.f);
          const size_t idx = (size_t)(bm + wm + i * 16 + cr + r) * ldc + col;
          if (WF32) Cf[idx] = v;
          if (WBF16) Cb[idx] = (short)f2bf(v);
        }
      }
    }
  }
}

// ---------------- MFMA flash attention (swapped QK^T), KV split ----------------
__global__ __launch_bounds__(256) void flash_attn_mfma_kernel(const short* __restrict__ qkvb,
                                                              float* __restrict__ Opart,
                                                              float* __restrict__ stats) {
  constexpr int LS = 72;
  __shared__ short Ks[64 * LS];
  __shared__ short Vt[64 * LS];  // transposed: row = d, col = key
  __shared__ short Ps[64 * LS];  // row = query(0..63), col = key
  const int h = blockIdx.y;
  const int q0 = blockIdx.x * 64;
  const int sp = blockIdx.z;
  const int tid = (int)threadIdx.x;
  const int lane = tid & 63;
  const int wid = tid >> 6;
  const int fr = lane & 15;
  const int g = lane >> 4;
  const int kg = g * 8;

  bf16x8 qf[2];
  {
    const short* src = qkvb + (size_t)(q0 + wid * 16 + fr) * (3 * DD) + h * DHD + kg;
    qf[0] = *(const bf16x8*)src;
    qf[1] = *(const bf16x8*)(src + 32);
  }

  f32x4 acc_o[4];
#pragma unroll
  for (int df = 0; df < 4; ++df) acc_o[df] = (f32x4){0.f, 0.f, 0.f, 0.f};
  float mreg = -INFINITY, lsum = 0.f;

  const int sr8 = tid >> 3;
  const int sc8 = (tid & 7) * 8;
  const int vk = tid & 63;
  const int vd = (tid >> 6) * 8;

  for (int t = 0; t < KVS / 64; ++t) {
    const int k0 = sp * KVS + t * 64;
    __syncthreads();
    {
#pragma unroll
      for (int p = 0; p < 64; p += 32)
        *(bf16x8*)&Ks[(sr8 + p) * LS + sc8] =
            *(const bf16x8*)&qkvb[(size_t)(k0 + sr8 + p) * (3 * DD) + DD + h * DHD + sc8];
#pragma unroll
      for (int p = 0; p < 64; p += 32) {
        const bf16x8 v = *(const bf16x8*)&qkvb[(size_t)(k0 + vk) * (3 * DD) + 2 * DD + h * DHD + vd + p];
#pragma unroll
        for (int j = 0; j < 8; ++j) Vt[(vd + p + j) * LS + vk] = v[j];
      }
    }
    __syncthreads();

    f32x4 st[4];
#pragma unroll
    for (int nf = 0; nf < 4; ++nf) st[nf] = (f32x4){0.f, 0.f, 0.f, 0.f};
#pragma unroll
    for (int nf = 0; nf < 4; ++nf) {
      const bf16x8 kf0 = *(const bf16x8*)&Ks[(nf * 16 + fr) * LS + kg];
      const bf16x8 kf1 = *(const bf16x8*)&Ks[(nf * 16 + fr) * LS + kg + 32];
      st[nf] = __builtin_amdgcn_mfma_f32_16x16x32_bf16(kf0, qf[0], st[nf], 0, 0, 0);
      st[nf] = __builtin_amdgcn_mfma_f32_16x16x32_bf16(kf1, qf[1], st[nf], 0, 0, 0);
    }

    float mx = st[0][0];
#pragma unroll
    for (int nf = 0; nf < 4; ++nf)
#pragma unroll
      for (int i = 0; i < 4; ++i) mx = fmaxf(mx, st[nf][i]);
    mx *= 0.125f;
    mx = fmaxf(mx, __shfl_xor(mx, 16, 64));
    mx = fmaxf(mx, __shfl_xor(mx, 32, 64));
    const float mn = fmaxf(mreg, mx);
    const float corr = __expf(mreg - mn);
    mreg = mn;
    float pv[4][4];
    float sum = 0.f;
#pragma unroll
    for (int nf = 0; nf < 4; ++nf)
#pragma unroll
      for (int i = 0; i < 4; ++i) {
        pv[nf][i] = __expf(fmaf(st[nf][i], 0.125f, -mn));
        sum += pv[nf][i];
      }
    sum += __shfl_xor(sum, 16, 64);
    sum += __shfl_xor(sum, 32, 64);
    lsum = lsum * corr + sum;

    float corr_acc[4];
#pragma unroll
    for (int i = 0; i < 4; ++i)
      corr_acc[i] = __shfl(corr, (lane & 48) | (g * 4 + i), 64);
#pragma unroll
    for (int df = 0; df < 4; ++df) {
      acc_o[df][0] *= corr_acc[0]; acc_o[df][1] *= corr_acc[1];
      acc_o[df][2] *= corr_acc[2]; acc_o[df][3] *= corr_acc[3];
    }

#pragma unroll
    for (int nf = 0; nf < 4; ++nf) {
      bf16x4 pw;
#pragma unroll
      for (int i = 0; i < 4; ++i) pw[i] = (short)f2bf(pv[nf][i]);
      *(bf16x4*)&Ps[(wid * 16 + fr) * LS + nf * 16 + g * 4] = pw;
    }
    asm volatile("s_waitcnt lgkmcnt(0)" ::: "memory");

    const bf16x8 pa0 = *(const bf16x8*)&Ps[(wid * 16 + fr) * LS + kg];
    const bf16x8 pa1 = *(const bf16x8*)&Ps[(wid * 16 + fr) * LS + kg + 32];
#pragma unroll
    for (int df = 0; df < 4; ++df) {
      const bf16x8 vb0 = *(const bf16x8*)&Vt[(df * 16 + fr) * LS + kg];
      const bf16x8 vb1 = *(const bf16x8*)&Vt[(df * 16 + fr) * LS + kg + 32];
      acc_o[df] = __builtin_amdgcn_mfma_f32_16x16x32_bf16(pa0, vb0, acc_o[df], 0, 0, 0);
      acc_o[df] = __builtin_amdgcn_mfma_f32_16x16x32_bf16(pa1, vb1, acc_o[df], 0, 0, 0);
    }
  }

  const int orow = q0 + wid * 16 + g * 4;
#pragma unroll
  for (int df = 0; df < 4; ++df)
#pragma unroll
    for (int i = 0; i < 4; ++i)
      Opart[((size_t)sp * PP + orow + i) * DD + h * DHD + df * 16 + fr] = acc_o[df][i];
  if (g == 0) {
    const size_t si = (((size_t)sp * PP + q0 + wid * 16 + fr) * HN + h) * 2;
    stats[si]     = mreg;
    stats[si + 1] = lsum;
  }
}

// ---------------- combine NS partials -> attno bf16 ----------------
__global__ __launch_bounds__(256) void attn_combine_kernel(const float* __restrict__ Opart,
                                                           const float* __restrict__ stats,
                                                           short* __restrict__ outb) {
  const int row = blockIdx.x;
  const int d = (int)threadIdx.x * 2;
  const int h = d >> 6;
  float m[NS], l[NS];
  float M = -INFINITY;
#pragma unroll
  for (int s = 0; s < NS; ++s) {
    const size_t si = (((size_t)s * PP + row) * HN + h) * 2;
    m[s] = stats[si]; l[s] = stats[si + 1];
    M = fmaxf(M, m[s]);
  }
  float L = 0.f, o0 = 0.f, o1 = 0.f;
#pragma unroll
  for (int s = 0; s < NS; ++s) {
    const float e = __expf(m[s] - M);
    L += l[s] * e;
    const float* op = Opart + ((size_t)s * PP + row) * DD + d;
    o0 += op[0] * e;
    o1 += op[1] * e;
  }
  const float inv = 1.f / L;
  outb[(size_t)row * DD + d]     = (short)f2bf(o0 * inv);
  outb[(size_t)row * DD + d + 1] = (short)f2bf(o1 * inv);
}

// ---------------- LN(x + P0 + P1 + gbias) * w + b -> fp32 + bf16 ----------------
__global__ __launch_bounds__(256) void ln_residual_kernel(const float* __restrict__ xin,
                                                          const float* __restrict__ pA,
                                                          const float* __restrict__ pB,
                                                          const float* __restrict__ gb,
                                                          const float* __restrict__ w,
                                                          const float* __restrict__ b,
                                                          float* __restrict__ out,
                                                          short* __restrict__ outb) {
  const int row = blockIdx.x * 4 + (threadIdx.x >> 6);
  const int lane = threadIdx.x & 63;
  const size_t base = (size_t)row * DD + lane * 8;
  float v[8];
  {
    const float4 a0 = *(const float4*)&xin[base];
    const float4 a1 = *(const float4*)&xin[base + 4];
    const float4 r0 = *(const float4*)&pA[base];
    const float4 r1 = *(const float4*)&pA[base + 4];
    const float4 s0 = *(const float4*)&pB[base];
    const float4 s1 = *(const float4*)&pB[base + 4];
    const float4 g0 = *(const float4*)&gb[lane * 8];
    const float4 g1 = *(const float4*)&gb[lane * 8 + 4];
    v[0] = a0.x + r0.x + s0.x + g0.x; v[1] = a0.y + r0.y + s0.y + g0.y;
    v[2] = a0.z + r0.z + s0.z + g0.z; v[3] = a0.w + r0.w + s0.w + g0.w;
    v[4] = a1.x + r1.x + s1.x + g1.x; v[5] = a1.y + r1.y + s1.y + g1.y;
    v[6] = a1.z + r1.z + s1.z + g1.z; v[7] = a1.w + r1.w + s1.w + g1.w;
  }
  float sum = 0.f;
#pragma unroll
  for (int j = 0; j < 8; ++j) sum += v[j];
  sum = wave_sum(sum);
  const float mean = sum * (1.f / DD);
  float sq = 0.f;
#pragma unroll
  for (int j = 0; j < 8; ++j) { const float dd = v[j] - mean; sq += dd * dd; }
  sq = wave_sum(sq);
  const float rstd = rsqrtf(sq * (1.f / DD) + EPS_);
  const float* wp = w + lane * 8;
  const float* bp = b + lane * 8;
  float o[8];
#pragma unroll
  for (int j = 0; j < 8; ++j) o[j] = (v[j] - mean) * rstd * wp[j] + bp[j];
  *(float4*)&out[base] = *(float4*)&o[0];
  *(float4*)&out[base + 4] = *(float4*)&o[4];
  bf16x8 ob;
#pragma unroll
  for (int j = 0; j < 8; ++j) ob[j] = (short)f2bf(o[j]);
  *(bf16x8*)&outb[base] = ob;
}

// ---------------- gate + mix (also emits enc_bf = bf16 of pre-mix x) ----------------
__global__ __launch_bounds__(256) void gate_mix_kernel(const float* __restrict__ tok,
                                                       const float* __restrict__ alpha_p,
                                                       float* __restrict__ x,
                                                       short* __restrict__ xb,
                                                       short* __restrict__ encb) {
  const int row = blockIdx.x * 4 + (threadIdx.x >> 6);
  const int lane = threadIdx.x & 63;
  const size_t base = (size_t)row * DD + lane * 8;
  float e[8], t[8];
  {
    const float4 a0 = *(const float4*)&x[base];
    const float4 a1 = *(const float4*)&x[base + 4];
    const float4 b0 = *(const float4*)&tok[base];
    const float4 b1 = *(const float4*)&tok[base + 4];
    e[0] = a0.x; e[1] = a0.y; e[2] = a0.z; e[3] = a0.w;
    e[4] = a1.x; e[5] = a1.y; e[6] = a1.z; e[7] = a1.w;
    t[0] = b0.x; t[1] = b0.y; t[2] = b0.z; t[3] = b0.w;
    t[4] = b1.x; t[5] = b1.y; t[6] = b1.z; t[7] = b1.w;
  }
  bf16x8 eb;
#pragma unroll
  for (int j = 0; j < 8; ++j) eb[j] = (short)f2bf(e[j]);
  *(bf16x8*)&encb[base] = eb;
  float sq = 0.f;
#pragma unroll
  for (int j = 0; j < 8; ++j) sq += e[j] * e[j];
  sq = wave_sum(sq);
  const bool gate = sq > TAU_ * TAU_;
  const float a = *alpha_p;
  float o[8];
#pragma unroll
  for (int j = 0; j < 8; ++j) o[j] = gate ? (a * e[j] + (1.f - a) * t[j]) : t[j];
  *(float4*)&x[base] = *(float4*)&o[0];
  *(float4*)&x[base + 4] = *(float4*)&o[4];
  bf16x8 ob;
#pragma unroll
  for (int j = 0; j < 8; ++j) ob[j] = (short)f2bf(o[j]);
  *(bf16x8*)&xb[base] = ob;
}

// ---------------- final out combine: d_out = P0 + P1 + bias ----------------
__global__ __launch_bounds__(256) void out_combine_kernel(const float* __restrict__ P0,
                                                          const float* __restrict__ P1,
                                                          const float* __restrict__ bias,
                                                          float* __restrict__ out) {
  const size_t i = ((size_t)blockIdx.x * 256 + threadIdx.x) * 4;
  const int col = (int)(i % VV);
  const float4 a = *(const float4*)&P0[i];
  const float4 b = *(const float4*)&P1[i];
  const float4 c = *(const float4*)&bias[col];
  float4 o;
  o.x = a.x + b.x + c.x; o.y = a.y + b.y + c.y;
  o.z = a.z + b.z + c.z; o.w = a.w + b.w + c.w;
  *(float4*)&out[i] = o;
}

// ---------------- launch ----------------
extern "C" void kernel_launch(void* const* d_in, const int* in_sizes, int n_in,
                              void* d_out, int out_size, void* d_ws, size_t ws_size,
                              hipStream_t stream) {
  const int*   bytes    = (const int*)d_in[0];
  const float* emb      = (const float*)d_in[1];
  const float* alpha    = (const float*)d_in[2];
  const float* enc_inw  = (const float*)d_in[3];
  const float* enc_inb  = (const float*)d_in[4];
  const float* enc_ow   = (const float*)d_in[5];
  const float* enc_ob   = (const float*)d_in[6];
  const float* enc_w1   = (const float*)d_in[7];
  const float* enc_b1   = (const float*)d_in[8];
  const float* enc_w2   = (const float*)d_in[9];
  const float* enc_b2   = (const float*)d_in[10];
  const float* enc_ln1w = (const float*)d_in[11];
  const float* enc_ln1b = (const float*)d_in[12];
  const float* enc_ln2w = (const float*)d_in[13];
  const float* enc_ln2b = (const float*)d_in[14];
  const float* dec_sa_inw = (const float*)d_in[15];
  const float* dec_sa_inb = (const float*)d_in[16];
  const float* dec_sa_ow  = (const float*)d_in[17];
  const float* dec_sa_ob  = (const float*)d_in[18];
  const float* dec_ca_inw = (const float*)d_in[19];
  const float* dec_ca_inb = (const float*)d_in[20];
  const float* dec_ca_ow  = (const float*)d_in[21];
  const float* dec_ca_ob  = (const float*)d_in[22];
  const float* dec_w1   = (const float*)d_in[23];
  const float* dec_b1   = (const float*)d_in[24];
  const float* dec_w2   = (const float*)d_in[25];
  const float* dec_b2   = (const float*)d_in[26];
  const float* dec_ln1w = (const float*)d_in[27];
  const float* dec_ln1b = (const float*)d_in[28];
  const float* dec_ln2w = (const float*)d_in[29];
  const float* dec_ln2b = (const float*)d_in[30];
  const float* dec_ln3w = (const float*)d_in[31];
  const float* dec_ln3b = (const float*)d_in[32];
  const float* out_w    = (const float*)d_in[33];
  const float* out_b    = (const float*)d_in[34];

  // ---- workspace layout ----
  float* fp = (float*)d_ws;
  float* x     = fp;  fp += (size_t)PP * DD;
  float* tok   = fp;  fp += (size_t)PP * DD;
  float* Opart = fp;  fp += (size_t)NS * PP * DD;
  float* stats = fp;  fp += (size_t)NS * PP * HN * 2;
  float* tmpP  = fp;  fp += (size_t)2 * PP * DD;     // split-K partials (P0,P1)
  float* outP  = fp;  fp += (size_t)2 * PP * VV;     // final-out partials
  short* sp = (short*)fp;
  short* x_bf    = sp;  sp += (size_t)PP * DD;
  short* enc_bf  = sp;  sp += (size_t)PP * DD;
  short* qkv_bf  = sp;  sp += (size_t)PP * 3 * DD;
  short* attno_bf= sp;  sp += (size_t)PP * DD;
  short* ffh_bf  = sp;  sp += (size_t)PP * DFF_;
  short* warena  = sp;  // ~41.1M shorts

  // ---- weight arena offsets + one-shot convert ----
  CvtArgs ca;
  size_t eoff[LL][4], doff[LL][6], ooff;
  {
    int si = 0;
    size_t off = 0;
    for (int l = 0; l < LL; ++l) {
      const size_t n0 = 3 * DD * DD, n1 = DD * DD, n2 = (size_t)DFF_ * DD, n3 = (size_t)DD * DFF_;
      ca.seg[si++] = {enc_inw + (size_t)l * n0, warena + off, (int)n0}; eoff[l][0] = off; off += n0;
      ca.seg[si++] = {enc_ow  + (size_t)l * n1, warena + off, (int)n1}; eoff[l][1] = off; off += n1;
      ca.seg[si++] = {enc_w1  + (size_t)l * n2, warena + off, (int)n2}; eoff[l][2] = off; off += n2;
      ca.seg[si++] = {enc_w2  + (size_t)l * n3, warena + off, (int)n3}; eoff[l][3] = off; off += n3;
    }
    for (int l = 0; l < LL; ++l) {
      const size_t n1 = DD * DD, n0 = 3 * DD * DD, n2 = (size_t)DFF_ * DD, n3 = (size_t)DD * DFF_;
      ca.seg[si++] = {dec_sa_inw + (size_t)l * n0 + 2 * n1, warena + off, (int)n1}; doff[l][0] = off; off += n1;
      ca.seg[si++] = {dec_sa_ow  + (size_t)l * n1,          warena + off, (int)n1}; doff[l][1] = off; off += n1;
      ca.seg[si++] = {dec_ca_inw + (size_t)l * n0,          warena + off, (int)n0}; doff[l][2] = off; off += n0;
      ca.seg[si++] = {dec_ca_ow  + (size_t)l * n1,          warena + off, (int)n1}; doff[l][3] = off; off += n1;
      ca.seg[si++] = {dec_w1     + (size_t)l * n2,          warena + off, (int)n2}; doff[l][4] = off; off += n2;
      ca.seg[si++] = {dec_w2     + (size_t)l * n3,          warena + off, (int)n3}; doff[l][5] = off; off += n3;
    }
    ca.seg[si++] = {out_w, warena + off, VV * DD}; ooff = off;
  }

  const dim3 b256(256);
  const dim3 gFA(PP / 64, HN, NS);
  const dim3 gQKV(3 * DD / 64, PP / 128);          // <128,64>: 24x16=384
  const dim3 gFF1(DFF_ / 64, PP / 128);            // <128,64>: 32x16=512
  const dim3 gS(DD / 64, PP / 64, 2);              // <64,64> splitK2: 8x32x2=512
  const dim3 gS1(DD / 64, PP / 64);                // <64,64>: 8x32=256
  const dim3 gKV(2 * DD / 64, PP / 64);            // <64,64>: 16x32=512
  const dim3 gOUTg(VV / 64, PP / 64, 2);           // <64,64> splitK2: 4x32x2=256
  const size_t psD = (size_t)PP * DD;
  const size_t psV = (size_t)PP * VV;

  convert_bf16_kernel<<<dim3(512, NSEG), b256, 0, stream>>>(ca);
  embed_mean_kernel<<<PP, b256, 0, stream>>>(bytes, emb, x, x_bf, tok);

  // ---------------- encoder ----------------
  for (int l = 0; l < LL; ++l) {
    const float* inb = enc_inb + (size_t)l * 3 * DD;
    const float* ob  = enc_ob  + (size_t)l * DD;
    const float* b1  = enc_b1  + (size_t)l * DFF_;
    const float* b2  = enc_b2  + (size_t)l * DD;

    gemm_gl_kernel<128, 64, 1, 0, 0, 1><<<gQKV, b256, 0, stream>>>(
        x_bf, DD, warena + eoff[l][0], DD, inb, nullptr, qkv_bf, 3 * DD, DD, 0);
    flash_attn_mfma_kernel<<<gFA, b256, 0, stream>>>(qkv_bf, Opart, stats);
    attn_combine_kernel<<<PP, b256, 0, stream>>>(Opart, stats, attno_bf);
    gemm_gl_kernel<64, 64, 2, 0, 1, 0><<<gS, b256, 0, stream>>>(
        attno_bf, DD, warena + eoff[l][1], DD, nullptr, tmpP, nullptr, DD, DD, psD);
    ln_residual_kernel<<<PP / 4, b256, 0, stream>>>(
        x, tmpP, tmpP + psD, ob, enc_ln1w + (size_t)l * DD, enc_ln1b + (size_t)l * DD, x, x_bf);
    gemm_gl_kernel<128, 64, 1, 1, 0, 1><<<gFF1, b256, 0, stream>>>(
        x_bf, DD, warena + eoff[l][2], DD, b1, nullptr, ffh_bf, DFF_, DD, 0);
    gemm_gl_kernel<64, 64, 2, 0, 1, 0><<<gS, b256, 0, stream>>>(
        ffh_bf, DFF_, warena + eoff[l][3], DFF_, nullptr, tmpP, nullptr, DD, DFF_, psD);
    ln_residual_kernel<<<PP / 4, b256, 0, stream>>>(
        x, tmpP, tmpP + psD, b2, enc_ln2w + (size_t)l * DD, enc_ln2b + (size_t)l * DD, x, x_bf);
  }

  gate_mix_kernel<<<PP / 4, b256, 0, stream>>>(tok, alpha, x, x_bf, enc_bf);

  // ---------------- decoder ----------------
  for (int l = 0; l < LL; ++l) {
    const float* sa_bv = dec_sa_inb + (size_t)l * 3 * DD + 2 * DD;
    const float* sa_ob = dec_sa_ob + (size_t)l * DD;
    const float* ca_inb = dec_ca_inb + (size_t)l * 3 * DD;
    const float* ca_ob  = dec_ca_ob + (size_t)l * DD;
    const float* b1 = dec_b1 + (size_t)l * DFF_;
    const float* b2 = dec_b2 + (size_t)l * DD;

    // self path (value-only)
    gemm_gl_kernel<64, 64, 1, 0, 0, 1><<<gS1, b256, 0, stream>>>(
        x_bf, DD, warena + doff[l][0], DD, sa_bv, nullptr, attno_bf, DD, DD, 0);
    gemm_gl_kernel<64, 64, 2, 0, 1, 0><<<gS, b256, 0, stream>>>(
        attno_bf, DD, warena + doff[l][1], DD, nullptr, tmpP, nullptr, DD, DD, psD);
    ln_residual_kernel<<<PP / 4, b256, 0, stream>>>(
        x, tmpP, tmpP + psD, sa_ob, dec_ln1w + (size_t)l * DD, dec_ln1b + (size_t)l * DD, x, x_bf);

    // cross-attention
    gemm_gl_kernel<64, 64, 1, 0, 0, 1><<<gS1, b256, 0, stream>>>(
        x_bf, DD, warena + doff[l][2], DD, ca_inb, nullptr, qkv_bf, 3 * DD, DD, 0);
    gemm_gl_kernel<64, 64, 1, 0, 0, 1><<<gKV, b256, 0, stream>>>(
        enc_bf, DD, warena + doff[l][2] + (size_t)DD * DD, DD, ca_inb + DD, nullptr,
        qkv_bf + DD, 3 * DD, DD, 0);
    flash_attn_mfma_kernel<<<gFA, b256, 0, stream>>>(qkv_bf, Opart, stats);
    attn_combine_kernel<<<PP, b256, 0, stream>>>(Opart, stats, attno_bf);
    gemm_gl_kernel<64, 64, 2, 0, 1, 0><<<gS, b256, 0, stream>>>(
        attno_bf, DD, warena + doff[l][3], DD, nullptr, tmpP, nullptr, DD, DD, psD);
    ln_residual_kernel<<<PP / 4, b256, 0, stream>>>(
        x, tmpP, tmpP + psD, ca_ob, dec_ln2w + (size_t)l * DD, dec_ln2b + (size_t)l * DD, x, x_bf);

    // FFN
    gemm_gl_kernel<128, 64, 1, 1, 0, 1><<<gFF1, b256, 0, stream>>>(
        x_bf, DD, warena + doff[l][4], DD, b1, nullptr, ffh_bf, DFF_, DD, 0);
    gemm_gl_kernel<64, 64, 2, 0, 1, 0><<<gS, b256, 0, stream>>>(
        ffh_bf, DFF_, warena + doff[l][5], DFF_, nullptr, tmpP, nullptr, DD, DFF_, psD);
    ln_residual_kernel<<<PP / 4, b256, 0, stream>>>(
        x, tmpP, tmpP + psD, b2, dec_ln3w + (size_t)l * DD, dec_ln3b + (size_t)l * DD, x, x_bf);
  }

  // final projection (split-K) + combine
  gemm_gl_kernel<64, 64, 2, 0, 1, 0><<<gOUTg, b256, 0, stream>>>(
      x_bf, DD, warena + ooff, DD, nullptr, outP, nullptr, VV, DD, psV);
  out_combine_kernel<<<(PP * VV / 4) / 256, b256, 0, stream>>>(
      outP, outP + psV, out_b, (float*)d_out);
}

// Round 6
// 1109.771 us; speedup vs baseline: 5.1918x; 1.1106x over previous
//
#include <hip/hip_runtime.h>
#include <hip/hip_bf16.h>
#include <math.h>

#define DD   512
#define HN   8
#define DHD  64
#define LL   6
#define DFF_ 2048
#define VV   256
#define KB_  5
#define PP   2048
#define EPS_ 1e-5f
#define TAU_ 0.1f
#define NS   4          // KV splits for flash attention
#define KVS  (PP / NS)  // 512 keys per split

typedef __attribute__((ext_vector_type(8))) short bf16x8;
typedef __attribute__((ext_vector_type(4))) short bf16x4;
typedef __attribute__((ext_vector_type(4))) float f32x4;

// ---------------- helpers ----------------
__device__ __forceinline__ float wave_sum(float v) {
#pragma unroll
  for (int m = 32; m >= 1; m >>= 1) v += __shfl_xor(v, m, 64);
  return v;
}

__device__ __forceinline__ unsigned short f2bf(float f) {
  unsigned u = __float_as_uint(f);
  u += 0x7FFF + ((u >> 16) & 1);   // RNE
  return (unsigned short)(u >> 16);
}

__device__ __forceinline__ bf16x8 cvt8(float4 a, float4 b) {
  bf16x8 v;
  v[0] = (short)f2bf(a.x); v[1] = (short)f2bf(a.y);
  v[2] = (short)f2bf(a.z); v[3] = (short)f2bf(a.w);
  v[4] = (short)f2bf(b.x); v[5] = (short)f2bf(b.y);
  v[6] = (short)f2bf(b.z); v[7] = (short)f2bf(b.w);
  return v;
}

__device__ __forceinline__ void gload16(const void* g, void* l) {
  __builtin_amdgcn_global_load_lds(
      (const __attribute__((address_space(1))) unsigned int*)g,
      (__attribute__((address_space(3))) unsigned int*)l, 16, 0, 0);
}

// ---------------- batched fp32 -> bf16 convert ----------------
#define NSEG 55
struct CvtSeg { const float* src; short* dst; int n; };
struct CvtArgs { CvtSeg seg[NSEG]; };

__global__ __launch_bounds__(256) void convert_bf16_kernel(CvtArgs a) {
  const CvtSeg sg = a.seg[blockIdx.y];
  const int i = ((int)blockIdx.x * 256 + (int)threadIdx.x) * 8;
  if (i >= sg.n) return;
  const float4 x0 = *(const float4*)(sg.src + i);
  const float4 x1 = *(const float4*)(sg.src + i + 4);
  *(bf16x8*)(sg.dst + i) = cvt8(x0, x1);
}

// ---------------- Wv transpose+convert: WvT[l][i][o] = Wv[l][o][i] (bf16) ----------------
__global__ __launch_bounds__(256) void transpose_wv_kernel(const float* __restrict__ sa_inw,
                                                           short* __restrict__ wvt) {
  __shared__ float t[64][65];
  const int l = blockIdx.z;
  const float* S = sa_inw + (size_t)l * 3 * DD * DD + (size_t)2 * DD * DD;
  short* D = wvt + (size_t)l * DD * DD;
  const int bo = blockIdx.y * 64;   // o-range
  const int bi = blockIdx.x * 64;   // i-range
  const int r = (int)threadIdx.x >> 2;
  const int c0 = ((int)threadIdx.x & 3) * 16;
#pragma unroll
  for (int j = 0; j < 16; j += 4)
    *(float4*)&t[r][c0 + j] = *(const float4*)&S[(size_t)(bo + r) * DD + bi + c0 + j];
  __syncthreads();
  // out row i = bi + r, cols o = bo + c0 .. +15 ; value = t[o-bo][i-bi]
  bf16x8 o0, o1;
#pragma unroll
  for (int j = 0; j < 8; ++j) o0[j] = (short)f2bf(t[c0 + j][r]);
#pragma unroll
  for (int j = 0; j < 8; ++j) o1[j] = (short)f2bf(t[c0 + 8 + j][r]);
  short* dp = &D[(size_t)(bi + r) * DD + bo + c0];
  *(bf16x8*)dp = o0;
  *(bf16x8*)(dp + 8) = o1;
}

// ---------------- sa bias combine: bc[l][n] = Wo[l][n]·bv[l] + bo[l][n] ----------------
__global__ __launch_bounds__(256) void sa_bias_kernel(const float* __restrict__ sa_inb,
                                                      const float* __restrict__ sa_ow,
                                                      const float* __restrict__ sa_ob,
                                                      float* __restrict__ bc) {
  const int gid = (int)blockIdx.x * 4 + ((int)threadIdx.x >> 6);  // 0..3071
  const int l = gid >> 9, n = gid & 511;
  const int lane = (int)threadIdx.x & 63;
  const float* wo = sa_ow + (size_t)l * DD * DD + (size_t)n * DD + lane * 8;
  const float* bv = sa_inb + (size_t)l * 3 * DD + 2 * DD + lane * 8;
  float s = 0.f;
#pragma unroll
  for (int j = 0; j < 8; ++j) s += wo[j] * bv[j];
  s = wave_sum(s);
  if (lane == 0) bc[(size_t)l * DD + n] = s + sa_ob[(size_t)l * DD + n];
}

// ---------------- batched Wc = Wo @ Wv (bf16 in, bf16 out), 6 layers ----------------
__global__ __launch_bounds__(256) void gemm_wc_kernel(const short* __restrict__ WoBase,
                                                      size_t astr,
                                                      const short* __restrict__ WvT,
                                                      short* __restrict__ Wc) {
  constexpr int BK = 64;
  __shared__ short As[64 * BK];
  __shared__ short Bs[64 * BK];
  const int l = blockIdx.z;
  const short* A = WoBase + (size_t)l * astr;
  const short* W = WvT + (size_t)l * DD * DD;
  short* C = Wc + (size_t)l * DD * DD;
  const int tid = (int)threadIdx.x;
  const int lane = tid & 63;
  const int wid = tid >> 6;
  const int wm = (wid >> 1) * 32;
  const int wn = (wid & 1) * 32;
  const int bm = blockIdx.y * 64;
  const int bn = blockIdx.x * 64;
  const int fr = lane & 15;
  const int kq = lane >> 4;
  const int rs = fr & 7;
  const int srow = lane >> 3;
  const int scg = (lane & 7) ^ srow;

  f32x4 acc[2][2];
#pragma unroll
  for (int i = 0; i < 2; ++i)
#pragma unroll
    for (int j = 0; j < 2; ++j) acc[i][j] = (f32x4){0.f, 0.f, 0.f, 0.f};

  for (int k0 = 0; k0 < DD; k0 += BK) {
    __syncthreads();
#pragma unroll
    for (int is = 0; is < 2; ++is) {
      const int ib = is * 4 + wid;
      gload16(&A[(size_t)(bm + ib * 8 + srow) * DD + k0 + scg * 8], &As[ib * 512]);
      gload16(&W[(size_t)(bn + ib * 8 + srow) * DD + k0 + scg * 8], &Bs[ib * 512]);
    }
    __syncthreads();
#pragma unroll
    for (int s = 0; s < 2; ++s) {
      const int cg = s * 4 + kq;
      const int co = (cg ^ rs) * 8;
      bf16x8 af[2], bf[2];
#pragma unroll
      for (int i = 0; i < 2; ++i) af[i] = *(const bf16x8*)&As[(wm + i * 16 + fr) * BK + co];
#pragma unroll
      for (int j = 0; j < 2; ++j) bf[j] = *(const bf16x8*)&Bs[(wn + j * 16 + fr) * BK + co];
#pragma unroll
      for (int i = 0; i < 2; ++i)
#pragma unroll
        for (int j = 0; j < 2; ++j)
          acc[i][j] = __builtin_amdgcn_mfma_f32_16x16x32_bf16(af[i], bf[j], acc[i][j], 0, 0, 0);
    }
  }
  const int cr = (lane >> 4) * 4;
#pragma unroll
  for (int j = 0; j < 2; ++j) {
    const int col = bn + wn + j * 16 + fr;
#pragma unroll
    for (int i = 0; i < 2; ++i)
#pragma unroll
      for (int r = 0; r < 4; ++r)
        C[(size_t)(bm + wm + i * 16 + cr + r) * DD + col] = (short)f2bf(acc[i][j][r]);
  }
}

// ---------------- embedding ----------------
__global__ __launch_bounds__(256) void embed_mean_kernel(const int* __restrict__ bytes,
                                                         const float* __restrict__ emb,
                                                         float* __restrict__ x,
                                                         short* __restrict__ xb,
                                                         float* __restrict__ tok) {
  const int p = blockIdx.x;
  const int d = threadIdx.x * 2;
  float a0 = 0.f, a1 = 0.f;
  int last = 0;
#pragma unroll
  for (int k = 0; k < KB_; ++k) {
    const int idx = bytes[p * KB_ + k];
    last = idx;
    const float* e = emb + (size_t)idx * DD + d;
    a0 += e[0]; a1 += e[1];
  }
  a0 *= 0.2f; a1 *= 0.2f;
  x[(size_t)p * DD + d]     = a0;
  x[(size_t)p * DD + d + 1] = a1;
  xb[(size_t)p * DD + d]     = (short)f2bf(a0);
  xb[(size_t)p * DD + d + 1] = (short)f2bf(a1);
  const float* e = emb + (size_t)last * DD + d;
  tok[(size_t)p * DD + d]     = e[0];
  tok[(size_t)p * DD + d + 1] = e[1];
}

// ---------------- MFMA GEMM with global_load_lds + XOR-swizzled LDS ----------------
// QS: multiply output by 0.125 when col < DD (pre-scales q for attention).
template <int BM, int BN, int NSPLIT, int RELU, int WF32, int WBF16, int QS>
__global__ __launch_bounds__(256) void gemm_gl_kernel(
    const short* __restrict__ A, int lda,
    const short* __restrict__ W, int ldw,
    const float* __restrict__ bias,
    float* __restrict__ Cf, short* __restrict__ Cb, int ldc, int Kd,
    size_t pstride) {
  constexpr int BK = 64;
  __shared__ short As[BM * BK];
  __shared__ short Bs[BN * BK];
  constexpr int WM = BM / 2, WN = BN / 2;
  constexpr int MF = WM / 16, NF = WN / 16;
  const int tid = (int)threadIdx.x;
  const int lane = tid & 63;
  const int wid = tid >> 6;
  const int wm = (wid >> 1) * WM;
  const int wn = (wid & 1) * WN;
  const int bm = blockIdx.y * BM;
  const int bn = blockIdx.x * BN;
  const int fr = lane & 15;
  const int kq = lane >> 4;
  const int rs = fr & 7;
  const int srow = lane >> 3;
  const int scg = (lane & 7) ^ srow;

  const int kz = (NSPLIT > 1) ? (int)blockIdx.z : 0;
  const int kbeg = kz * (Kd / NSPLIT);
  const int kend = kbeg + Kd / NSPLIT;

  f32x4 acc[MF][NF];
#pragma unroll
  for (int i = 0; i < MF; ++i)
#pragma unroll
    for (int j = 0; j < NF; ++j) acc[i][j] = (f32x4){0.f, 0.f, 0.f, 0.f};

  for (int k0 = kbeg; k0 < kend; k0 += BK) {
    __syncthreads();
#pragma unroll
    for (int is = 0; is < BM / 32; ++is) {
      const int ib = is * 4 + wid;
      gload16(&A[(size_t)(bm + ib * 8 + srow) * lda + k0 + scg * 8], &As[ib * 512]);
    }
#pragma unroll
    for (int is = 0; is < BN / 32; ++is) {
      const int ib = is * 4 + wid;
      gload16(&W[(size_t)(bn + ib * 8 + srow) * ldw + k0 + scg * 8], &Bs[ib * 512]);
    }
    __syncthreads();
#pragma unroll
    for (int s = 0; s < 2; ++s) {
      const int cg = s * 4 + kq;
      const int co = (cg ^ rs) * 8;
      bf16x8 af[MF], bf[NF];
#pragma unroll
      for (int i = 0; i < MF; ++i)
        af[i] = *(const bf16x8*)&As[(wm + i * 16 + fr) * BK + co];
#pragma unroll
      for (int j = 0; j < NF; ++j)
        bf[j] = *(const bf16x8*)&Bs[(wn + j * 16 + fr) * BK + co];
#pragma unroll
      for (int i = 0; i < MF; ++i)
#pragma unroll
        for (int j = 0; j < NF; ++j)
          acc[i][j] = __builtin_amdgcn_mfma_f32_16x16x32_bf16(af[i], bf[j], acc[i][j], 0, 0, 0);
    }
  }

  const int cr = (lane >> 4) * 4;
  if constexpr (NSPLIT > 1) {
    float* dst = Cf + (size_t)kz * pstride;
#pragma unroll
    for (int j = 0; j < NF; ++j) {
      const int col = bn + wn + j * 16 + fr;
#pragma unroll
      for (int i = 0; i < MF; ++i)
#pragma unroll
        for (int r = 0; r < 4; ++r)
          dst[(size_t)(bm + wm + i * 16 + cr + r) * ldc + col] = acc[i][j][r];
    }
  } else {
#pragma unroll
    for (int j = 0; j < NF; ++j) {
      const int col = bn + wn + j * 16 + fr;
      const float bb = bias[col];
      const float sc = (QS && col < DD) ? 0.125f : 1.f;
#pragma unroll
      for (int i = 0; i < MF; ++i) {
#pragma unroll
        for (int r = 0; r < 4; ++r) {
          float v = (acc[i][j][r] + bb) * sc;
          if (RELU) v = fmaxf(v, 0.f);
          const size_t idx = (size_t)(bm + wm + i * 16 + cr + r) * ldc + col;
          if (WF32) Cf[idx] = v;
          if (WBF16) Cb[idx] = (short)f2bf(v);
        }
      }
    }
  }
}

// ---------------- merged decoder cross-attn projections (q from x, kv from enc) ----------------
// grid (24, 32): bx<8 -> q part (scaled 0.125), else kv part. Output into qkv_bf (ld 3D).
__global__ __launch_bounds__(256) void gemm_ca_kernel(
    const short* __restrict__ Aq, const short* __restrict__ Akv,
    const short* __restrict__ Wfull, const float* __restrict__ bias,
    short* __restrict__ Cb) {
  constexpr int BK = 64;
  __shared__ short As[64 * BK];
  __shared__ short Bs[64 * BK];
  const int bx = (int)blockIdx.x;
  const int part_kv = bx >= 8;
  const short* A = part_kv ? Akv : Aq;
  const int wrow0 = part_kv ? DD + (bx - 8) * 64 : bx * 64;
  const float sc = part_kv ? 1.f : 0.125f;
  const int tid = (int)threadIdx.x;
  const int lane = tid & 63;
  const int wid = tid >> 6;
  const int wm = (wid >> 1) * 32;
  const int wn = (wid & 1) * 32;
  const int bm = blockIdx.y * 64;
  const int fr = lane & 15;
  const int kq = lane >> 4;
  const int rs = fr & 7;
  const int srow = lane >> 3;
  const int scg = (lane & 7) ^ srow;

  f32x4 acc[2][2];
#pragma unroll
  for (int i = 0; i < 2; ++i)
#pragma unroll
    for (int j = 0; j < 2; ++j) acc[i][j] = (f32x4){0.f, 0.f, 0.f, 0.f};

  for (int k0 = 0; k0 < DD; k0 += BK) {
    __syncthreads();
#pragma unroll
    for (int is = 0; is < 2; ++is) {
      const int ib = is * 4 + wid;
      gload16(&A[(size_t)(bm + ib * 8 + srow) * DD + k0 + scg * 8], &As[ib * 512]);
      gload16(&Wfull[(size_t)(wrow0 + ib * 8 + srow) * DD + k0 + scg * 8], &Bs[ib * 512]);
    }
    __syncthreads();
#pragma unroll
    for (int s = 0; s < 2; ++s) {
      const int cg = s * 4 + kq;
      const int co = (cg ^ rs) * 8;
      bf16x8 af[2], bf[2];
#pragma unroll
      for (int i = 0; i < 2; ++i) af[i] = *(const bf16x8*)&As[(wm + i * 16 + fr) * BK + co];
#pragma unroll
      for (int j = 0; j < 2; ++j) bf[j] = *(const bf16x8*)&Bs[(wn + j * 16 + fr) * BK + co];
#pragma unroll
      for (int i = 0; i < 2; ++i)
#pragma unroll
        for (int j = 0; j < 2; ++j)
          acc[i][j] = __builtin_amdgcn_mfma_f32_16x16x32_bf16(af[i], bf[j], acc[i][j], 0, 0, 0);
    }
  }
  const int cr = (lane >> 4) * 4;
#pragma unroll
  for (int j = 0; j < 2; ++j) {
    const int col = wrow0 + wn + j * 16 + fr;
    const float bb = bias[col];
#pragma unroll
    for (int i = 0; i < 2; ++i)
#pragma unroll
      for (int r = 0; r < 4; ++r)
        Cb[(size_t)(bm + wm + i * 16 + cr + r) * (3 * DD) + col] =
            (short)f2bf((acc[i][j][r] + bb) * sc);
  }
}

// ---------------- MFMA flash attention (swapped QK^T, q pre-scaled), KV split ----------------
__global__ __launch_bounds__(256) void flash_attn_mfma_kernel(const short* __restrict__ qkvb,
                                                              float* __restrict__ Opart,
                                                              float* __restrict__ stats) {
  constexpr int LS = 72;
  __shared__ short Ks[64 * LS];
  __shared__ short Vt[64 * LS];  // transposed: row = d, col = key
  __shared__ short Ps[64 * LS];  // row = query(0..63), col = key
  const int h = blockIdx.y;
  const int q0 = blockIdx.x * 64;
  const int sp = blockIdx.z;
  const int tid = (int)threadIdx.x;
  const int lane = tid & 63;
  const int wid = tid >> 6;
  const int fr = lane & 15;
  const int g = lane >> 4;
  const int kg = g * 8;

  bf16x8 qf[2];
  {
    const short* src = qkvb + (size_t)(q0 + wid * 16 + fr) * (3 * DD) + h * DHD + kg;
    qf[0] = *(const bf16x8*)src;
    qf[1] = *(const bf16x8*)(src + 32);
  }

  f32x4 acc_o[4];
#pragma unroll
  for (int df = 0; df < 4; ++df) acc_o[df] = (f32x4){0.f, 0.f, 0.f, 0.f};
  float mreg = -INFINITY, lsum = 0.f;

  const int sr8 = tid >> 3;
  const int sc8 = (tid & 7) * 8;
  const int vk2 = (tid & 31) * 2;      // even key
  const int vd8 = (tid >> 5) * 8;      // 8 d's

  for (int t = 0; t < KVS / 64; ++t) {
    const int k0 = sp * KVS + t * 64;
    __syncthreads();
    {
#pragma unroll
      for (int p = 0; p < 64; p += 32)
        *(bf16x8*)&Ks[(sr8 + p) * LS + sc8] =
            *(const bf16x8*)&qkvb[(size_t)(k0 + sr8 + p) * (3 * DD) + DD + h * DHD + sc8];
      // V: load 2 keys x 8 d, pack key-pairs into dwords -> b32 writes
      const short* vbase = qkvb + (size_t)(k0 + vk2) * (3 * DD) + 2 * DD + h * DHD + vd8;
      const bf16x8 v0 = *(const bf16x8*)vbase;
      const bf16x8 v1 = *(const bf16x8*)(vbase + 3 * DD);
#pragma unroll
      for (int j = 0; j < 8; ++j) {
        const unsigned pk = ((unsigned)(unsigned short)v0[j]) |
                            (((unsigned)(unsigned short)v1[j]) << 16);
        *(unsigned*)&Vt[(vd8 + j) * LS + vk2] = pk;
      }
    }
    __syncthreads();

    f32x4 st[4];
#pragma unroll
    for (int nf = 0; nf < 4; ++nf) st[nf] = (f32x4){0.f, 0.f, 0.f, 0.f};
    __builtin_amdgcn_s_setprio(1);
#pragma unroll
    for (int nf = 0; nf < 4; ++nf) {
      const bf16x8 kf0 = *(const bf16x8*)&Ks[(nf * 16 + fr) * LS + kg];
      const bf16x8 kf1 = *(const bf16x8*)&Ks[(nf * 16 + fr) * LS + kg + 32];
      st[nf] = __builtin_amdgcn_mfma_f32_16x16x32_bf16(kf0, qf[0], st[nf], 0, 0, 0);
      st[nf] = __builtin_amdgcn_mfma_f32_16x16x32_bf16(kf1, qf[1], st[nf], 0, 0, 0);
    }
    __builtin_amdgcn_s_setprio(0);

    float mx = st[0][0];
#pragma unroll
    for (int nf = 0; nf < 4; ++nf)
#pragma unroll
      for (int i = 0; i < 4; ++i) mx = fmaxf(mx, st[nf][i]);
    mx = fmaxf(mx, __shfl_xor(mx, 16, 64));
    mx = fmaxf(mx, __shfl_xor(mx, 32, 64));
    const float mn = fmaxf(mreg, mx);
    const float corr = __expf(mreg - mn);
    mreg = mn;
    float pv[4][4];
    float sum = 0.f;
#pragma unroll
    for (int nf = 0; nf < 4; ++nf)
#pragma unroll
      for (int i = 0; i < 4; ++i) {
        pv[nf][i] = __expf(st[nf][i] - mn);
        sum += pv[nf][i];
      }
    sum += __shfl_xor(sum, 16, 64);
    sum += __shfl_xor(sum, 32, 64);
    lsum = lsum * corr + sum;

    float corr_acc[4];
#pragma unroll
    for (int i = 0; i < 4; ++i)
      corr_acc[i] = __shfl(corr, (lane & 48) | (g * 4 + i), 64);
#pragma unroll
    for (int df = 0; df < 4; ++df) {
      acc_o[df][0] *= corr_acc[0]; acc_o[df][1] *= corr_acc[1];
      acc_o[df][2] *= corr_acc[2]; acc_o[df][3] *= corr_acc[3];
    }

#pragma unroll
    for (int nf = 0; nf < 4; ++nf) {
      bf16x4 pw;
#pragma unroll
      for (int i = 0; i < 4; ++i) pw[i] = (short)f2bf(pv[nf][i]);
      *(bf16x4*)&Ps[(wid * 16 + fr) * LS + nf * 16 + g * 4] = pw;
    }
    asm volatile("s_waitcnt lgkmcnt(0)" ::: "memory");

    const bf16x8 pa0 = *(const bf16x8*)&Ps[(wid * 16 + fr) * LS + kg];
    const bf16x8 pa1 = *(const bf16x8*)&Ps[(wid * 16 + fr) * LS + kg + 32];
    __builtin_amdgcn_s_setprio(1);
#pragma unroll
    for (int df = 0; df < 4; ++df) {
      const bf16x8 vb0 = *(const bf16x8*)&Vt[(df * 16 + fr) * LS + kg];
      const bf16x8 vb1 = *(const bf16x8*)&Vt[(df * 16 + fr) * LS + kg + 32];
      acc_o[df] = __builtin_amdgcn_mfma_f32_16x16x32_bf16(pa0, vb0, acc_o[df], 0, 0, 0);
      acc_o[df] = __builtin_amdgcn_mfma_f32_16x16x32_bf16(pa1, vb1, acc_o[df], 0, 0, 0);
    }
    __builtin_amdgcn_s_setprio(0);
  }

  const int orow = q0 + wid * 16 + g * 4;
#pragma unroll
  for (int df = 0; df < 4; ++df)
#pragma unroll
    for (int i = 0; i < 4; ++i)
      Opart[((size_t)sp * PP + orow + i) * DD + h * DHD + df * 16 + fr] = acc_o[df][i];
  if (g == 0) {
    const size_t si = (((size_t)sp * PP + q0 + wid * 16 + fr) * HN + h) * 2;
    stats[si]     = mreg;
    stats[si + 1] = lsum;
  }
}

// ---------------- combine NS partials -> attno bf16 ----------------
__global__ __launch_bounds__(256) void attn_combine_kernel(const float* __restrict__ Opart,
                                                           const float* __restrict__ stats,
                                                           short* __restrict__ outb) {
  const int row = blockIdx.x;
  const int d = (int)threadIdx.x * 2;
  const int h = d >> 6;
  float m[NS], l[NS];
  float M = -INFINITY;
#pragma unroll
  for (int s = 0; s < NS; ++s) {
    const size_t si = (((size_t)s * PP + row) * HN + h) * 2;
    m[s] = stats[si]; l[s] = stats[si + 1];
    M = fmaxf(M, m[s]);
  }
  float L = 0.f, o0 = 0.f, o1 = 0.f;
#pragma unroll
  for (int s = 0; s < NS; ++s) {
    const float e = __expf(m[s] - M);
    L += l[s] * e;
    const float* op = Opart + ((size_t)s * PP + row) * DD + d;
    o0 += op[0] * e;
    o1 += op[1] * e;
  }
  const float inv = 1.f / L;
  outb[(size_t)row * DD + d]     = (short)f2bf(o0 * inv);
  outb[(size_t)row * DD + d + 1] = (short)f2bf(o1 * inv);
}

// ---------------- LN(x + P0 + P1 + gbias) * w + b -> fp32 + bf16 ----------------
__global__ __launch_bounds__(256) void ln_residual_kernel(const float* __restrict__ xin,
                                                          const float* __restrict__ pA,
                                                          const float* __restrict__ pB,
                                                          const float* __restrict__ gb,
                                                          const float* __restrict__ w,
                                                          const float* __restrict__ b,
                                                          float* __restrict__ out,
                                                          short* __restrict__ outb) {
  const int row = blockIdx.x * 4 + (threadIdx.x >> 6);
  const int lane = threadIdx.x & 63;
  const size_t base = (size_t)row * DD + lane * 8;
  float v[8];
  {
    const float4 a0 = *(const float4*)&xin[base];
    const float4 a1 = *(const float4*)&xin[base + 4];
    const float4 r0 = *(const float4*)&pA[base];
    const float4 r1 = *(const float4*)&pA[base + 4];
    const float4 s0 = *(const float4*)&pB[base];
    const float4 s1 = *(const float4*)&pB[base + 4];
    const float4 g0 = *(const float4*)&gb[lane * 8];
    const float4 g1 = *(const float4*)&gb[lane * 8 + 4];
    v[0] = a0.x + r0.x + s0.x + g0.x; v[1] = a0.y + r0.y + s0.y + g0.y;
    v[2] = a0.z + r0.z + s0.z + g0.z; v[3] = a0.w + r0.w + s0.w + g0.w;
    v[4] = a1.x + r1.x + s1.x + g1.x; v[5] = a1.y + r1.y + s1.y + g1.y;
    v[6] = a1.z + r1.z + s1.z + g1.z; v[7] = a1.w + r1.w + s1.w + g1.w;
  }
  float sum = 0.f;
#pragma unroll
  for (int j = 0; j < 8; ++j) sum += v[j];
  sum = wave_sum(sum);
  const float mean = sum * (1.f / DD);
  float sq = 0.f;
#pragma unroll
  for (int j = 0; j < 8; ++j) { const float dd = v[j] - mean; sq += dd * dd; }
  sq = wave_sum(sq);
  const float rstd = rsqrtf(sq * (1.f / DD) + EPS_);
  const float* wp = w + lane * 8;
  const float* bp = b + lane * 8;
  float o[8];
#pragma unroll
  for (int j = 0; j < 8; ++j) o[j] = (v[j] - mean) * rstd * wp[j] + bp[j];
  *(float4*)&out[base] = *(float4*)&o[0];
  *(float4*)&out[base + 4] = *(float4*)&o[4];
  bf16x8 ob;
#pragma unroll
  for (int j = 0; j < 8; ++j) ob[j] = (short)f2bf(o[j]);
  *(bf16x8*)&outb[base] = ob;
}

// ---------------- gate + mix (also emits enc_bf = bf16 of pre-mix x) ----------------
__global__ __launch_bounds__(256) void gate_mix_kernel(const float* __restrict__ tok,
                                                       const float* __restrict__ alpha_p,
                                                       float* __restrict__ x,
                                                       short* __restrict__ xb,
                                                       short* __restrict__ encb) {
  const int row = blockIdx.x * 4 + (threadIdx.x >> 6);
  const int lane = threadIdx.x & 63;
  const size_t base = (size_t)row * DD + lane * 8;
  float e[8], t[8];
  {
    const float4 a0 = *(const float4*)&x[base];
    const float4 a1 = *(const float4*)&x[base + 4];
    const float4 b0 = *(const float4*)&tok[base];
    const float4 b1 = *(const float4*)&tok[base + 4];
    e[0] = a0.x; e[1] = a0.y; e[2] = a0.z; e[3] = a0.w;
    e[4] = a1.x; e[5] = a1.y; e[6] = a1.z; e[7] = a1.w;
    t[0] = b0.x; t[1] = b0.y; t[2] = b0.z; t[3] = b0.w;
    t[4] = b1.x; t[5] = b1.y; t[6] = b1.z; t[7] = b1.w;
  }
  bf16x8 eb;
#pragma unroll
  for (int j = 0; j < 8; ++j) eb[j] = (short)f2bf(e[j]);
  *(bf16x8*)&encb[base] = eb;
  float sq = 0.f;
#pragma unroll
  for (int j = 0; j < 8; ++j) sq += e[j] * e[j];
  sq = wave_sum(sq);
  const bool gate = sq > TAU_ * TAU_;
  const float a = *alpha_p;
  float o[8];
#pragma unroll
  for (int j = 0; j < 8; ++j) o[j] = gate ? (a * e[j] + (1.f - a) * t[j]) : t[j];
  *(float4*)&x[base] = *(float4*)&o[0];
  *(float4*)&x[base + 4] = *(float4*)&o[4];
  bf16x8 ob;
#pragma unroll
  for (int j = 0; j < 8; ++j) ob[j] = (short)f2bf(o[j]);
  *(bf16x8*)&xb[base] = ob;
}

// ---------------- final out combine: d_out = P0 + P1 + bias ----------------
__global__ __launch_bounds__(256) void out_combine_kernel(const float* __restrict__ P0,
                                                          const float* __restrict__ P1,
                                                          const float* __restrict__ bias,
                                                          float* __restrict__ out) {
  const size_t i = ((size_t)blockIdx.x * 256 + threadIdx.x) * 4;
  const int col = (int)(i % VV);
  const float4 a = *(const float4*)&P0[i];
  const float4 b = *(const float4*)&P1[i];
  const float4 c = *(const float4*)&bias[col];
  float4 o;
  o.x = a.x + b.x + c.x; o.y = a.y + b.y + c.y;
  o.z = a.z + b.z + c.z; o.w = a.w + b.w + c.w;
  *(float4*)&out[i] = o;
}

// ---------------- launch ----------------
extern "C" void kernel_launch(void* const* d_in, const int* in_sizes, int n_in,
                              void* d_out, int out_size, void* d_ws, size_t ws_size,
                              hipStream_t stream) {
  const int*   bytes    = (const int*)d_in[0];
  const float* emb      = (const float*)d_in[1];
  const float* alpha    = (const float*)d_in[2];
  const float* enc_inw  = (const float*)d_in[3];
  const float* enc_inb  = (const float*)d_in[4];
  const float* enc_ow   = (const float*)d_in[5];
  const float* enc_ob   = (const float*)d_in[6];
  const float* enc_w1   = (const float*)d_in[7];
  const float* enc_b1   = (const float*)d_in[8];
  const float* enc_w2   = (const float*)d_in[9];
  const float* enc_b2   = (const float*)d_in[10];
  const float* enc_ln1w = (const float*)d_in[11];
  const float* enc_ln1b = (const float*)d_in[12];
  const float* enc_ln2w = (const float*)d_in[13];
  const float* enc_ln2b = (const float*)d_in[14];
  const float* dec_sa_inw = (const float*)d_in[15];
  const float* dec_sa_inb = (const float*)d_in[16];
  const float* dec_sa_ow  = (const float*)d_in[17];
  const float* dec_sa_ob  = (const float*)d_in[18];
  const float* dec_ca_inw = (const float*)d_in[19];
  const float* dec_ca_inb = (const float*)d_in[20];
  const float* dec_ca_ow  = (const float*)d_in[21];
  const float* dec_ca_ob  = (const float*)d_in[22];
  const float* dec_w1   = (const float*)d_in[23];
  const float* dec_b1   = (const float*)d_in[24];
  const float* dec_w2   = (const float*)d_in[25];
  const float* dec_b2   = (const float*)d_in[26];
  const float* dec_ln1w = (const float*)d_in[27];
  const float* dec_ln1b = (const float*)d_in[28];
  const float* dec_ln2w = (const float*)d_in[29];
  const float* dec_ln2b = (const float*)d_in[30];
  const float* dec_ln3w = (const float*)d_in[31];
  const float* dec_ln3b = (const float*)d_in[32];
  const float* out_w    = (const float*)d_in[33];
  const float* out_b    = (const float*)d_in[34];

  // ---- workspace layout ----
  float* fp = (float*)d_ws;
  float* x     = fp;  fp += (size_t)PP * DD;
  float* tok   = fp;  fp += (size_t)PP * DD;
  float* Opart = fp;  fp += (size_t)NS * PP * DD;
  float* stats = fp;  fp += (size_t)NS * PP * HN * 2;
  float* tmpP  = fp;  fp += (size_t)2 * PP * DD;     // split-K partials (P0,P1)
  float* outP  = fp;  fp += (size_t)2 * PP * VV;     // final-out partials
  float* bcbuf = fp;  fp += (size_t)LL * DD;         // fused sa bias
  short* sp = (short*)fp;
  short* x_bf    = sp;  sp += (size_t)PP * DD;
  short* enc_bf  = sp;  sp += (size_t)PP * DD;
  short* qkv_bf  = sp;  sp += (size_t)PP * 3 * DD;
  short* attno_bf= sp;  sp += (size_t)PP * DFF_;     // reuse-sized
  short* ffh_bf  = sp;  sp += (size_t)PP * DFF_;
  short* wvT     = sp;  sp += (size_t)LL * DD * DD;  // Wv transposed bf16
  short* wcM     = sp;  sp += (size_t)LL * DD * DD;  // fused Wc = Wo@Wv bf16
  short* warena  = sp;

  // ---- weight arena offsets + one-shot convert ----
  CvtArgs ca;
  size_t eoff[LL][4], doff[LL][5], ooff;
  size_t dec_start = 0, dec_stride = 0;
  {
    int si = 0;
    size_t off = 0;
    const size_t n0 = 3 * DD * DD, n1 = DD * DD, n2 = (size_t)DFF_ * DD, n3 = (size_t)DD * DFF_;
    for (int l = 0; l < LL; ++l) {
      ca.seg[si++] = {enc_inw + (size_t)l * n0, warena + off, (int)n0}; eoff[l][0] = off; off += n0;
      ca.seg[si++] = {enc_ow  + (size_t)l * n1, warena + off, (int)n1}; eoff[l][1] = off; off += n1;
      ca.seg[si++] = {enc_w1  + (size_t)l * n2, warena + off, (int)n2}; eoff[l][2] = off; off += n2;
      ca.seg[si++] = {enc_w2  + (size_t)l * n3, warena + off, (int)n3}; eoff[l][3] = off; off += n3;
    }
    dec_start = off;
    for (int l = 0; l < LL; ++l) {
      const size_t o0 = off;
      ca.seg[si++] = {dec_sa_ow  + (size_t)l * n1, warena + off, (int)n1}; doff[l][0] = off; off += n1;
      ca.seg[si++] = {dec_ca_inw + (size_t)l * n0, warena + off, (int)n0}; doff[l][1] = off; off += n0;
      ca.seg[si++] = {dec_ca_ow  + (size_t)l * n1, warena + off, (int)n1}; doff[l][2] = off; off += n1;
      ca.seg[si++] = {dec_w1     + (size_t)l * n2, warena + off, (int)n2}; doff[l][3] = off; off += n2;
      ca.seg[si++] = {dec_w2     + (size_t)l * n3, warena + off, (int)n3}; doff[l][4] = off; off += n3;
      if (l == 0) dec_stride = off - o0; (void)o0;
    }
    ca.seg[si++] = {out_w, warena + off, VV * DD}; ooff = off;
  }

  const dim3 b256(256);
  const dim3 gFA(PP / 64, HN, NS);
  const dim3 gQKV(3 * DD / 64, PP / 128);          // <128,64>: 24x16=384
  const dim3 gFF1(DFF_ / 64, PP / 128);            // <128,64>: 32x16=512
  const dim3 gS(DD / 64, PP / 64, 2);              // <64,64> splitK2: 8x32x2=512
  const dim3 gCA(24, PP / 64);                     // merged ca: 24x32=768
  const dim3 gOUTg(VV / 64, PP / 64, 2);           // <64,64> splitK2
  const size_t psD = (size_t)PP * DD;
  const size_t psV = (size_t)PP * VV;

  // prologue: convert, Wv transpose, sa bias fuse, Wc batched GEMM
  convert_bf16_kernel<<<dim3(512, NSEG), b256, 0, stream>>>(ca);
  transpose_wv_kernel<<<dim3(8, 8, LL), b256, 0, stream>>>(dec_sa_inw, wvT);
  sa_bias_kernel<<<(LL * DD) / 4, b256, 0, stream>>>(dec_sa_inb, dec_sa_ow, dec_sa_ob, bcbuf);
  gemm_wc_kernel<<<dim3(8, 8, LL), b256, 0, stream>>>(warena + dec_start, dec_stride, wvT, wcM);
  embed_mean_kernel<<<PP, b256, 0, stream>>>(bytes, emb, x, x_bf, tok);

  // ---------------- encoder ----------------
  for (int l = 0; l < LL; ++l) {
    const float* inb = enc_inb + (size_t)l * 3 * DD;
    const float* ob  = enc_ob  + (size_t)l * DD;
    const float* b1  = enc_b1  + (size_t)l * DFF_;
    const float* b2  = enc_b2  + (size_t)l * DD;

    gemm_gl_kernel<128, 64, 1, 0, 0, 1, 1><<<gQKV, b256, 0, stream>>>(
        x_bf, DD, warena + eoff[l][0], DD, inb, nullptr, qkv_bf, 3 * DD, DD, 0);
    flash_attn_mfma_kernel<<<gFA, b256, 0, stream>>>(qkv_bf, Opart, stats);
    attn_combine_kernel<<<PP, b256, 0, stream>>>(Opart, stats, attno_bf);
    gemm_gl_kernel<64, 64, 2, 0, 1, 0, 0><<<gS, b256, 0, stream>>>(
        attno_bf, DD, warena + eoff[l][1], DD, nullptr, tmpP, nullptr, DD, DD, psD);
    ln_residual_kernel<<<PP / 4, b256, 0, stream>>>(
        x, tmpP, tmpP + psD, ob, enc_ln1w + (size_t)l * DD, enc_ln1b + (size_t)l * DD, x, x_bf);
    gemm_gl_kernel<128, 64, 1, 1, 0, 1, 0><<<gFF1, b256, 0, stream>>>(
        x_bf, DD, warena + eoff[l][2], DD, b1, nullptr, ffh_bf, DFF_, DD, 0);
    gemm_gl_kernel<64, 64, 2, 0, 1, 0, 0><<<gS, b256, 0, stream>>>(
        ffh_bf, DFF_, warena + eoff[l][3], DFF_, nullptr, tmpP, nullptr, DD, DFF_, psD);
    ln_residual_kernel<<<PP / 4, b256, 0, stream>>>(
        x, tmpP, tmpP + psD, b2, enc_ln2w + (size_t)l * DD, enc_ln2b + (size_t)l * DD, x, x_bf);
  }

  gate_mix_kernel<<<PP / 4, b256, 0, stream>>>(tok, alpha, x, x_bf, enc_bf);

  // ---------------- decoder ----------------
  for (int l = 0; l < LL; ++l) {
    const float* ca_inb = dec_ca_inb + (size_t)l * 3 * DD;
    const float* ca_ob  = dec_ca_ob + (size_t)l * DD;
    const float* b1 = dec_b1 + (size_t)l * DFF_;
    const float* b2 = dec_b2 + (size_t)l * DD;

    // fused linear self path: x @ Wc^T, bias via LN's gb
    gemm_gl_kernel<64, 64, 2, 0, 1, 0, 0><<<gS, b256, 0, stream>>>(
        x_bf, DD, wcM + (size_t)l * DD * DD, DD, nullptr, tmpP, nullptr, DD, DD, psD);
    ln_residual_kernel<<<PP / 4, b256, 0, stream>>>(
        x, tmpP, tmpP + psD, bcbuf + (size_t)l * DD,
        dec_ln1w + (size_t)l * DD, dec_ln1b + (size_t)l * DD, x, x_bf);

    // merged cross-attention projections (q scaled)
    gemm_ca_kernel<<<gCA, b256, 0, stream>>>(
        x_bf, enc_bf, warena + doff[l][1], ca_inb, qkv_bf);
    flash_attn_mfma_kernel<<<gFA, b256, 0, stream>>>(qkv_bf, Opart, stats);
    attn_combine_kernel<<<PP, b256, 0, stream>>>(Opart, stats, attno_bf);
    gemm_gl_kernel<64, 64, 2, 0, 1, 0, 0><<<gS, b256, 0, stream>>>(
        attno_bf, DD, warena + doff[l][2], DD, nullptr, tmpP, nullptr, DD, DD, psD);
    ln_residual_kernel<<<PP / 4, b256, 0, stream>>>(
        x, tmpP, tmpP + psD, ca_ob, dec_ln2w + (size_t)l * DD, dec_ln2b + (size_t)l * DD, x, x_bf);

    // FFN
    gemm_gl_kernel<128, 64, 1, 1, 0, 1, 0><<<gFF1, b256, 0, stream>>>(
        x_bf, DD, warena + doff[l][3], DD, b1, nullptr, ffh_bf, DFF_, DD, 0);
    gemm_gl_kernel<64, 64, 2, 0, 1, 0, 0><<<gS, b256, 0, stream>>>(
        ffh_bf, DFF_, warena + doff[l][4], DFF_, nullptr, tmpP, nullptr, DD, DFF_, psD);
    ln_residual_kernel<<<PP / 4, b256, 0, stream>>>(
        x, tmpP, tmpP + psD, b2, dec_ln3w + (size_t)l * DD, dec_ln3b + (size_t)l * DD, x, x_bf);
  }

  // final projection (split-K) + combine
  gemm_gl_kernel<64, 64, 2, 0, 1, 0, 0><<<gOUTg, b256, 0, stream>>>(
      x_bf, DD, warena + ooff, DD, nullptr, outP, nullptr, VV, DD, psV);
  out_combine_kernel<<<(PP * VV / 4) / 256, b256, 0, stream>>>(
      outP, outP + psV, out_b, (float*)d_out);
}